// Round 1
// baseline (2435.143 us; speedup 1.0000x reference)
//
#include <hip/hip_runtime.h>

#define DIM 96
#define S 884736      // 96*96*96
#define C 64
#define HALF 32
#define PARTS 16
#define EPS 1e-5f

// ---------------- K1: per-channel partial sums (deterministic) ----------------
__global__ __launch_bounds__(256) void k1_stats(const float* __restrict__ x,
                                                float* __restrict__ psum,
                                                float* __restrict__ psq) {
  const int bid = blockIdx.x;              // 0 .. C*PARTS-1
  const int ch = bid / PARTS, part = bid % PARTS;
  const int chunk = S / PARTS;             // 55296
  const float4* p = (const float4*)(x + (size_t)ch * S + (size_t)part * chunk);
  const int n4 = chunk / 4;                // 13824
  float s = 0.f, q = 0.f;
  for (int i = threadIdx.x; i < n4; i += 256) {
    float4 v = p[i];
    s += (v.x + v.y) + (v.z + v.w);
    q += (v.x * v.x + v.y * v.y) + (v.z * v.z + v.w * v.w);
  }
  #pragma unroll
  for (int off = 32; off > 0; off >>= 1) {
    s += __shfl_down(s, off);
    q += __shfl_down(q, off);
  }
  __shared__ float ls[4], lq[4];
  const int wid = threadIdx.x >> 6, lane = threadIdx.x & 63;
  if (lane == 0) { ls[wid] = s; lq[wid] = q; }
  __syncthreads();
  if (threadIdx.x == 0) {
    psum[bid] = (ls[0] + ls[1]) + (ls[2] + ls[3]);
    psq[bid]  = (lq[0] + lq[1]) + (lq[2] + lq[3]);
  }
}

// ---------------- K1b: finalize stats, fold norm into in_proj, transpose W ----
__global__ __launch_bounds__(64) void k1b_prep(const float* __restrict__ psum,
    const float* __restrict__ psq,
    const float* __restrict__ norm_w, const float* __restrict__ norm_b,
    const float* __restrict__ in_w, const float* __restrict__ in_b,
    const float* __restrict__ out_w,
    float* __restrict__ WpT, float* __restrict__ biasp,
    float* __restrict__ WoutT) {
  __shared__ float a_s[C], b2_s[C];
  const int t = threadIdx.x;               // 0..63
  float s = 0.f, q = 0.f;
  for (int i = 0; i < PARTS; ++i) { s += psum[t * PARTS + i]; q += psq[t * PARTS + i]; }
  const float inv = 1.f / (float)S;
  const float mu = s * inv;
  const float var = q * inv - mu * mu;
  const float rsig = rsqrtf(var + EPS);
  const float a = norm_w[t] * rsig;
  const float b2 = norm_b[t] - mu * a;
  a_s[t] = a; b2_s[t] = b2;
  __syncthreads();
  float bp = in_b[t];
  for (int c = 0; c < C; ++c) {
    const float w = in_w[t * C + c];
    WpT[c * C + t] = w * a_s[c];           // folded norm scale
    bp += b2_s[c] * w;                     // folded norm shift
    WoutT[c * C + t] = out_w[t * C + c];   // transpose for contiguous per-c rows
  }
  biasp[t] = bp;
}

// ---------------- K2: (norm folded) 1x1 in_proj, 64 acc in VGPRs --------------
__global__ __launch_bounds__(256) void k2_inproj(const float* __restrict__ x,
    const float* __restrict__ WpT, const float* __restrict__ biasp,
    float* __restrict__ xp) {
  const int v = blockIdx.x * 256 + threadIdx.x;
  float acc[C];
  #pragma unroll
  for (int o = 0; o < C; ++o) acc[o] = biasp[o];
  for (int c = 0; c < C; ++c) {
    const float xc = x[(size_t)c * S + v];
    const float4* w4 = (const float4*)(WpT + c * C);   // wave-uniform -> s_load
    #pragma unroll
    for (int o4 = 0; o4 < C / 4; ++o4) {
      const float4 w = w4[o4];
      acc[o4 * 4 + 0] += xc * w.x;
      acc[o4 * 4 + 1] += xc * w.y;
      acc[o4 * 4 + 2] += xc * w.z;
      acc[o4 * 4 + 3] += xc * w.w;
    }
  }
  #pragma unroll
  for (int o = 0; o < C; ++o) xp[(size_t)o * S + v] = acc[o];
}

// ---------------- depthwise 3x3x3, SAME zero padding --------------------------
__device__ __forceinline__ float conv27(const float* __restrict__ src,
                                        int d, int h, int w,
                                        const float* __restrict__ kw, float bias) {
  float acc = bias;
  #pragma unroll
  for (int kd = 0; kd < 3; ++kd) {
    const int dd = d + kd - 1;
    #pragma unroll
    for (int kh = 0; kh < 3; ++kh) {
      const int hh = h + kh - 1;
      const bool okdh = ((unsigned)dd < DIM) && ((unsigned)hh < DIM);
      const float* row = src + ((size_t)dd * DIM + hh) * DIM;
      #pragma unroll
      for (int ki = 0; ki < 3; ++ki) {
        const int ww = w + ki - 1;
        if (okdh && ((unsigned)ww < DIM))
          acc += row[ww] * kw[kd * 9 + kh * 3 + ki];
      }
    }
  }
  return acc;
}

// ---------------- K3: x1 half: dwconv(ssm) + SiLU -> t1 -----------------------
__global__ __launch_bounds__(192) void k3_conv_silu(const float* __restrict__ xp,
    const float* __restrict__ ssm_w, const float* __restrict__ ssm_b,
    float* __restrict__ t1) {
  const int w = threadIdx.x;
  const int h = blockIdx.x * 2 + threadIdx.y;
  const int d = blockIdx.y;
  const int c = blockIdx.z;
  float acc = conv27(xp + (size_t)c * S, d, h, w, ssm_w + c * 27, ssm_b[c]);
  acc = acc / (1.f + __expf(-acc));        // SiLU
  t1[(size_t)c * S + ((size_t)d * DIM + h) * DIM + w] = acc;
}

// ---------------- K4: dwconv(mamba) | dwconv(sym)+SiLU | out_proj | residual --
__global__ __launch_bounds__(192) void k4_out(const float* __restrict__ t1,
    const float* __restrict__ xp, const float* __restrict__ x,
    const float* __restrict__ mw, const float* __restrict__ mb,
    const float* __restrict__ sw, const float* __restrict__ sb,
    const float* __restrict__ WoutT, const float* __restrict__ ob,
    float* __restrict__ out) {
  const int w = threadIdx.x;
  const int h = blockIdx.x * 2 + threadIdx.y;
  const int d = blockIdx.y;
  const size_t v = ((size_t)d * DIM + h) * DIM + w;
  float acc[C];
  #pragma unroll
  for (int o = 0; o < C; ++o) acc[o] = ob[o];
  // x1 half: second depthwise conv (no activation), accumulate out_proj on the fly
  for (int c = 0; c < HALF; ++c) {
    const float zc = conv27(t1 + (size_t)c * S, d, h, w, mw + c * 27, mb[c]);
    const float4* w4 = (const float4*)(WoutT + c * C);
    #pragma unroll
    for (int o4 = 0; o4 < C / 4; ++o4) {
      const float4 wv = w4[o4];
      acc[o4 * 4 + 0] += zc * wv.x;
      acc[o4 * 4 + 1] += zc * wv.y;
      acc[o4 * 4 + 2] += zc * wv.z;
      acc[o4 * 4 + 3] += zc * wv.w;
    }
  }
  // x2 half: dwconv(sym) + SiLU directly from xp (t2 never materialized)
  for (int c = 0; c < HALF; ++c) {
    const float s = conv27(xp + (size_t)(HALF + c) * S, d, h, w, sw + c * 27, sb[c]);
    const float zc = s / (1.f + __expf(-s));
    const float4* w4 = (const float4*)(WoutT + (HALF + c) * C);
    #pragma unroll
    for (int o4 = 0; o4 < C / 4; ++o4) {
      const float4 wv = w4[o4];
      acc[o4 * 4 + 0] += zc * wv.x;
      acc[o4 * 4 + 1] += zc * wv.y;
      acc[o4 * 4 + 2] += zc * wv.z;
      acc[o4 * 4 + 3] += zc * wv.w;
    }
  }
  #pragma unroll
  for (int o = 0; o < C; ++o)
    out[(size_t)o * S + v] = acc[o] + x[(size_t)o * S + v];
}

extern "C" void kernel_launch(void* const* d_in, const int* in_sizes, int n_in,
                              void* d_out, int out_size, void* d_ws, size_t ws_size,
                              hipStream_t stream) {
  const float* x      = (const float*)d_in[0];
  const float* norm_w = (const float*)d_in[1];
  const float* norm_b = (const float*)d_in[2];
  const float* in_w   = (const float*)d_in[3];
  const float* in_b   = (const float*)d_in[4];
  const float* ssm_w  = (const float*)d_in[5];
  const float* ssm_b  = (const float*)d_in[6];
  const float* mam_w  = (const float*)d_in[7];
  const float* mam_b  = (const float*)d_in[8];
  const float* sym_w  = (const float*)d_in[9];
  const float* sym_b  = (const float*)d_in[10];
  const float* out_w  = (const float*)d_in[11];
  const float* out_b  = (const float*)d_in[12];
  float* out = (float*)d_out;

  float* ws    = (float*)d_ws;
  float* xp    = ws;                               // C*S floats (226.5 MB)
  float* t1    = xp + (size_t)C * S;               // HALF*S floats (113.3 MB)
  float* st    = t1 + (size_t)HALF * S;
  float* psum  = st;                               // C*PARTS
  float* psq   = st + C * PARTS;                   // C*PARTS
  float* WpT   = st + 2 * C * PARTS;               // C*C
  float* biasp = WpT + C * C;                      // C
  float* WoutT = biasp + C;                        // C*C

  k1_stats<<<C * PARTS, 256, 0, stream>>>(x, psum, psq);
  k1b_prep<<<1, 64, 0, stream>>>(psum, psq, norm_w, norm_b, in_w, in_b, out_w,
                                 WpT, biasp, WoutT);
  k2_inproj<<<S / 256, 256, 0, stream>>>(x, WpT, biasp, xp);
  k3_conv_silu<<<dim3(DIM / 2, DIM, HALF), dim3(DIM, 2, 1), 0, stream>>>(
      xp, ssm_w, ssm_b, t1);
  k4_out<<<dim3(DIM / 2, DIM, 1), dim3(DIM, 2, 1), 0, stream>>>(
      t1, xp, x, mam_w, mam_b, sym_w, sym_b, WoutT, out_b, out);
}

// Round 2
// 940.049 us; speedup vs baseline: 2.5904x; 2.5904x over previous
//
#include <hip/hip_runtime.h>

#define DIM 96
#define S 884736      // 96*96*96
#define C 64
#define HALF 32
#define PARTS 16
#define EPS 1e-5f

// ---------------- K1: per-channel partial sums (deterministic) ----------------
__global__ __launch_bounds__(256) void k1_stats(const float* __restrict__ x,
                                                float* __restrict__ psum,
                                                float* __restrict__ psq) {
  const int bid = blockIdx.x;              // 0 .. C*PARTS-1
  const int ch = bid / PARTS, part = bid % PARTS;
  const int chunk = S / PARTS;             // 55296
  const float4* p = (const float4*)(x + (size_t)ch * S + (size_t)part * chunk);
  const int n4 = chunk / 4;                // 13824
  float s = 0.f, q = 0.f;
  for (int i = threadIdx.x; i < n4; i += 256) {
    float4 v = p[i];
    s += (v.x + v.y) + (v.z + v.w);
    q += (v.x * v.x + v.y * v.y) + (v.z * v.z + v.w * v.w);
  }
  #pragma unroll
  for (int off = 32; off > 0; off >>= 1) {
    s += __shfl_down(s, off);
    q += __shfl_down(q, off);
  }
  __shared__ float ls[4], lq[4];
  const int wid = threadIdx.x >> 6, lane = threadIdx.x & 63;
  if (lane == 0) { ls[wid] = s; lq[wid] = q; }
  __syncthreads();
  if (threadIdx.x == 0) {
    psum[bid] = (ls[0] + ls[1]) + (ls[2] + ls[3]);
    psq[bid]  = (lq[0] + lq[1]) + (lq[2] + lq[3]);
  }
}

// ---------------- K1b: finalize stats, fold norm into in_proj (row-major) -----
__global__ __launch_bounds__(64) void k1b_prep(const float* __restrict__ psum,
    const float* __restrict__ psq,
    const float* __restrict__ norm_w, const float* __restrict__ norm_b,
    const float* __restrict__ in_w, const float* __restrict__ in_b,
    float* __restrict__ Wp, float* __restrict__ biasp) {
  __shared__ float a_s[C], b2_s[C];
  const int t = threadIdx.x;               // 0..63
  float s = 0.f, q = 0.f;
  for (int i = 0; i < PARTS; ++i) { s += psum[t * PARTS + i]; q += psq[t * PARTS + i]; }
  const float inv = 1.f / (float)S;
  const float mu = s * inv;
  const float var = q * inv - mu * mu;
  const float rsig = rsqrtf(var + EPS);
  const float a = norm_w[t] * rsig;
  const float b2 = norm_b[t] - mu * a;
  a_s[t] = a; b2_s[t] = b2;
  __syncthreads();
  float bp = in_b[t];
  for (int c = 0; c < C; ++c) {
    const float w = in_w[t * C + c];
    Wp[t * C + c] = w * a_s[c];            // folded norm scale, row-major
    bp += b2_s[c] * w;                     // folded norm shift
  }
  biasp[t] = bp;
}

// ---------------- K2: 1x1 in_proj, dot-product style --------------------------
__global__ __launch_bounds__(256) void k2_inproj(const float* __restrict__ x,
    const float* __restrict__ Wp, const float* __restrict__ biasp,
    float* __restrict__ xp) {
  const int v = blockIdx.x * 256 + threadIdx.x;
  float xv[C];
  #pragma unroll
  for (int c = 0; c < C; ++c) xv[c] = x[(size_t)c * S + v];   // 64 pipelined loads
  for (int o = 0; o < C; ++o) {
    const float4* w4 = (const float4*)(Wp + o * C);           // wave-uniform
    float s0 = 0.f, s1 = 0.f, s2 = 0.f, s3 = 0.f;
    #pragma unroll
    for (int c4 = 0; c4 < C / 4; ++c4) {
      const float4 w = w4[c4];
      s0 += w.x * xv[4 * c4 + 0];
      s1 += w.y * xv[4 * c4 + 1];
      s2 += w.z * xv[4 * c4 + 2];
      s3 += w.w * xv[4 * c4 + 3];
    }
    xp[(size_t)o * S + v] = (s0 + s1) + (s2 + s3) + biasp[o];
  }
}

// ---------------- depthwise 3x3x3, 4-wide along w, SAME zero padding ----------
__device__ __forceinline__ float4 conv4(const float* __restrict__ src,
                                        const float* __restrict__ kw,
                                        float bias, int d, int h, int w4) {
  float a0 = bias, a1 = bias, a2 = bias, a3 = bias;
  #pragma unroll
  for (int kd = 0; kd < 3; ++kd) {
    const int dd = d + kd - 1;
    if ((unsigned)dd >= DIM) continue;
    #pragma unroll
    for (int kh = 0; kh < 3; ++kh) {
      const int hh = h + kh - 1;
      if ((unsigned)hh >= DIM) continue;
      const float* row = src + ((size_t)dd * DIM + hh) * DIM;
      const float t0 = kw[kd * 9 + kh * 3 + 0];
      const float t1 = kw[kd * 9 + kh * 3 + 1];
      const float t2 = kw[kd * 9 + kh * 3 + 2];
      const float  l0 = (w4 > 0) ? row[w4 - 1] : 0.f;
      const float4 m  = *(const float4*)(row + w4);
      const float  l5 = (w4 < DIM - 4) ? row[w4 + 4] : 0.f;
      a0 += t0 * l0  + t1 * m.x + t2 * m.y;
      a1 += t0 * m.x + t1 * m.y + t2 * m.z;
      a2 += t0 * m.y + t1 * m.z + t2 * m.w;
      a3 += t0 * m.z + t1 * m.w + t2 * l5;
    }
  }
  return make_float4(a0, a1, a2, a3);
}

__device__ __forceinline__ float silu(float v) { return v / (1.f + __expf(-v)); }

// ---------------- K3: both first-stage convs (+SiLU) --------------------------
// c < 32 : t1[c] = SiLU(conv_ssm(xp[c]))
// c >= 32: z[c]  = SiLU(conv_sym(xp[c]))   (z lives in d_out)
__global__ __launch_bounds__(192) void k3_convs(const float* __restrict__ xp,
    const float* __restrict__ ssm_w, const float* __restrict__ ssm_b,
    const float* __restrict__ sym_w, const float* __restrict__ sym_b,
    float* __restrict__ t1, float* __restrict__ z) {
  const int w4 = threadIdx.x * 4;
  const int h  = blockIdx.x * 8 + threadIdx.y;
  const int d  = blockIdx.y;
  const int c  = blockIdx.z;
  const float* src; const float* kw; float bias; float* dst;
  if (c < HALF) { src = xp + (size_t)c * S; kw = ssm_w + c * 27; bias = ssm_b[c];       dst = t1 + (size_t)c * S; }
  else          { src = xp + (size_t)c * S; kw = sym_w + (c - HALF) * 27; bias = sym_b[c - HALF]; dst = z + (size_t)c * S; }
  float4 a = conv4(src, kw, bias, d, h, w4);
  a.x = silu(a.x); a.y = silu(a.y); a.z = silu(a.z); a.w = silu(a.w);
  *(float4*)(dst + ((size_t)d * DIM + h) * DIM + w4) = a;
}

// ---------------- K4a: mamba conv (no activation): z[c] = conv_m(t1[c]) -------
__global__ __launch_bounds__(192) void k4a_conv(const float* __restrict__ t1,
    const float* __restrict__ mw, const float* __restrict__ mb,
    float* __restrict__ z) {
  const int w4 = threadIdx.x * 4;
  const int h  = blockIdx.x * 8 + threadIdx.y;
  const int d  = blockIdx.y;
  const int c  = blockIdx.z;
  float4 a = conv4(t1 + (size_t)c * S, mw + c * 27, mb[c], d, h, w4);
  *(float4*)(z + (size_t)c * S + ((size_t)d * DIM + h) * DIM + w4) = a;
}

// ---------------- K4b: in-place 1x1 out_proj + bias + residual ----------------
__global__ __launch_bounds__(256) void k4b_out(const float* __restrict__ x,
    const float* __restrict__ out_w, const float* __restrict__ ob,
    float* __restrict__ out) {
  const int v = blockIdx.x * 256 + threadIdx.x;
  float zv[C];
  #pragma unroll
  for (int c = 0; c < C; ++c) zv[c] = out[(size_t)c * S + v];  // read full column
  for (int o = 0; o < C; ++o) {
    const float4* w4 = (const float4*)(out_w + o * C);         // wave-uniform
    float s0 = 0.f, s1 = 0.f, s2 = 0.f, s3 = 0.f;
    #pragma unroll
    for (int c4 = 0; c4 < C / 4; ++c4) {
      const float4 w = w4[c4];
      s0 += w.x * zv[4 * c4 + 0];
      s1 += w.y * zv[4 * c4 + 1];
      s2 += w.z * zv[4 * c4 + 2];
      s3 += w.w * zv[4 * c4 + 3];
    }
    out[(size_t)o * S + v] = (s0 + s1) + (s2 + s3) + ob[o] + x[(size_t)o * S + v];
  }
}

extern "C" void kernel_launch(void* const* d_in, const int* in_sizes, int n_in,
                              void* d_out, int out_size, void* d_ws, size_t ws_size,
                              hipStream_t stream) {
  const float* x      = (const float*)d_in[0];
  const float* norm_w = (const float*)d_in[1];
  const float* norm_b = (const float*)d_in[2];
  const float* in_w   = (const float*)d_in[3];
  const float* in_b   = (const float*)d_in[4];
  const float* ssm_w  = (const float*)d_in[5];
  const float* ssm_b  = (const float*)d_in[6];
  const float* mam_w  = (const float*)d_in[7];
  const float* mam_b  = (const float*)d_in[8];
  const float* sym_w  = (const float*)d_in[9];
  const float* sym_b  = (const float*)d_in[10];
  const float* out_w  = (const float*)d_in[11];
  const float* out_b  = (const float*)d_in[12];
  float* out = (float*)d_out;

  float* ws    = (float*)d_ws;
  float* xp    = ws;                               // C*S floats (226.5 MB)
  float* t1    = xp + (size_t)C * S;               // HALF*S floats (113.3 MB)
  float* st    = t1 + (size_t)HALF * S;
  float* psum  = st;                               // C*PARTS
  float* psq   = st + C * PARTS;                   // C*PARTS
  float* Wp    = st + 2 * C * PARTS;               // C*C
  float* biasp = Wp + C * C;                       // C

  k1_stats<<<C * PARTS, 256, 0, stream>>>(x, psum, psq);
  k1b_prep<<<1, 64, 0, stream>>>(psum, psq, norm_w, norm_b, in_w, in_b, Wp, biasp);
  k2_inproj<<<S / 256, 256, 0, stream>>>(x, Wp, biasp, xp);
  k3_convs<<<dim3(12, DIM, C), dim3(24, 8, 1), 0, stream>>>(
      xp, ssm_w, ssm_b, sym_w, sym_b, t1, out);
  k4a_conv<<<dim3(12, DIM, HALF), dim3(24, 8, 1), 0, stream>>>(t1, mam_w, mam_b, out);
  k4b_out<<<S / 256, 256, 0, stream>>>(x, out_w, out_b, out);
}

// Round 3
// 786.143 us; speedup vs baseline: 3.0976x; 1.1958x over previous
//
#include <hip/hip_runtime.h>

#define DIM 96
#define PLANE (DIM*DIM)   // 9216
#define S 884736          // 96^3
#define C 64
#define HALF 32
#define PARTS 16
#define EPS 1e-5f
#define DSPLIT 4
#define DCHUNK (DIM/DSPLIT)  // 24, divisible by 3 (ring rotation stays static)

// ---------------- K1: per-channel partial sums (deterministic) ----------------
__global__ __launch_bounds__(256) void k1_stats(const float* __restrict__ x,
                                                float* __restrict__ psum,
                                                float* __restrict__ psq) {
  const int bid = blockIdx.x;              // 0 .. C*PARTS-1
  const int ch = bid / PARTS, part = bid % PARTS;
  const int chunk = S / PARTS;             // 55296
  const float4* p = (const float4*)(x + (size_t)ch * S + (size_t)part * chunk);
  const int n4 = chunk / 4;                // 13824
  float s = 0.f, q = 0.f;
  for (int i = threadIdx.x; i < n4; i += 256) {
    float4 v = p[i];
    s += (v.x + v.y) + (v.z + v.w);
    q += (v.x * v.x + v.y * v.y) + (v.z * v.z + v.w * v.w);
  }
  #pragma unroll
  for (int off = 32; off > 0; off >>= 1) {
    s += __shfl_down(s, off);
    q += __shfl_down(q, off);
  }
  __shared__ float ls[4], lq[4];
  const int wid = threadIdx.x >> 6, lane = threadIdx.x & 63;
  if (lane == 0) { ls[wid] = s; lq[wid] = q; }
  __syncthreads();
  if (threadIdx.x == 0) {
    psum[bid] = (ls[0] + ls[1]) + (ls[2] + ls[3]);
    psq[bid]  = (lq[0] + lq[1]) + (lq[2] + lq[3]);
  }
}

// ---------------- K1b: finalize stats, fold norm into in_proj (row-major) -----
__global__ __launch_bounds__(64) void k1b_prep(const float* __restrict__ psum,
    const float* __restrict__ psq,
    const float* __restrict__ norm_w, const float* __restrict__ norm_b,
    const float* __restrict__ in_w, const float* __restrict__ in_b,
    float* __restrict__ Wp, float* __restrict__ biasp) {
  __shared__ float a_s[C], b2_s[C];
  const int t = threadIdx.x;               // 0..63
  float s = 0.f, q = 0.f;
  for (int i = 0; i < PARTS; ++i) { s += psum[t * PARTS + i]; q += psq[t * PARTS + i]; }
  const float inv = 1.f / (float)S;
  const float mu = s * inv;
  const float var = q * inv - mu * mu;
  const float rsig = rsqrtf(var + EPS);
  const float a = norm_w[t] * rsig;
  const float b2 = norm_b[t] - mu * a;
  a_s[t] = a; b2_s[t] = b2;
  __syncthreads();
  float bp = in_b[t];
  for (int c = 0; c < C; ++c) {
    const float w = in_w[t * C + c];
    Wp[t * C + c] = w * a_s[c];            // folded norm scale, row-major
    bp += b2_s[c] * w;                     // folded norm shift
  }
  biasp[t] = bp;
}

// ---------------- K2: 1x1 in_proj, dot-product style --------------------------
__global__ __launch_bounds__(256) void k2_inproj(const float* __restrict__ x,
    const float* __restrict__ Wp, const float* __restrict__ biasp,
    float* __restrict__ xp) {
  const int v = blockIdx.x * 256 + threadIdx.x;
  float xv[C];
  #pragma unroll
  for (int c = 0; c < C; ++c) xv[c] = x[(size_t)c * S + v];   // 64 pipelined loads
  for (int o = 0; o < C; ++o) {
    const float4* w4 = (const float4*)(Wp + o * C);           // wave-uniform
    float s0 = 0.f, s1 = 0.f, s2 = 0.f, s3 = 0.f;
    #pragma unroll
    for (int c4 = 0; c4 < C / 4; ++c4) {
      const float4 w = w4[c4];
      s0 += w.x * xv[4 * c4 + 0];
      s1 += w.y * xv[4 * c4 + 1];
      s2 += w.z * xv[4 * c4 + 2];
      s3 += w.w * xv[4 * c4 + 3];
    }
    xp[(size_t)o * S + v] = (s0 + s1) + (s2 + s3) + biasp[o];
  }
}

// ---------------- sliding-window depthwise 3x3x3 ------------------------------
struct Row { float lo; float4 m; float hi; };

__device__ __forceinline__ void zero_row(Row& r) {
  r.lo = 0.f; r.m = make_float4(0.f, 0.f, 0.f, 0.f); r.hi = 0.f;
}

__device__ __forceinline__ void load_row(Row& r, const float* __restrict__ src,
                                         int dd, int hh, int w4, bool hok) {
  if (hok) {
    const float* row = src + (size_t)dd * PLANE + hh * DIM;
    r.lo = (w4 > 0) ? row[w4 - 1] : 0.f;
    r.m  = *(const float4*)(row + w4);
    r.hi = (w4 < DIM - 4) ? row[w4 + 4] : 0.f;
  } else {
    zero_row(r);
  }
}

__device__ __forceinline__ void fma_row(float4& a, const Row& r,
                                        float t0, float t1, float t2) {
  a.x += t0 * r.lo  + t1 * r.m.x + t2 * r.m.y;
  a.y += t0 * r.m.x + t1 * r.m.y + t2 * r.m.z;
  a.z += t0 * r.m.y + t1 * r.m.z + t2 * r.m.w;
  a.w += t0 * r.m.z + t1 * r.m.w + t2 * r.hi;
}

__device__ __forceinline__ float silu(float v) { return v / (1.f + __expf(-v)); }

// One launch = 32 channels. Thread owns (w4..w4+3, h) strip, walks DCHUNK d's.
template<bool SILU>
__global__ __launch_bounds__(192) void dwconv(const float* __restrict__ src0,
    const float* __restrict__ kw0, const float* __restrict__ b0,
    float* __restrict__ dst0) {
  const int c = blockIdx.z;
  const float* src = src0 + (size_t)c * S;
  float* dst = dst0 + (size_t)c * S;
  const float* kwp = kw0 + c * 27;         // wave-uniform
  float kw[27];
  #pragma unroll
  for (int i = 0; i < 27; ++i) kw[i] = kwp[i];
  const float bias = b0[c];

  const int w4 = threadIdx.x * 4;
  const int h  = blockIdx.x * 8 + threadIdx.y;
  const bool hm = h > 0, hp = h < DIM - 1;
  const int d0 = blockIdx.y * DCHUNK;      // multiple of 24 -> d0 % 3 == 0

  Row W[3][3];                             // [plane ring dd%3][kh]
  if (d0 > 0) {
    load_row(W[2][0], src, d0 - 1, h - 1, w4, hm);
    load_row(W[2][1], src, d0 - 1, h,     w4, true);
    load_row(W[2][2], src, d0 - 1, h + 1, w4, hp);
  } else { zero_row(W[2][0]); zero_row(W[2][1]); zero_row(W[2][2]); }
  load_row(W[0][0], src, d0, h - 1, w4, hm);
  load_row(W[0][1], src, d0, h,     w4, true);
  load_row(W[0][2], src, d0, h + 1, w4, hp);

  #define STEP(D, PM, PC, PP) { \
    const int dd = (D) + 1; \
    if (dd < DIM) { \
      load_row(W[PP][0], src, dd, h - 1, w4, hm); \
      load_row(W[PP][1], src, dd, h,     w4, true); \
      load_row(W[PP][2], src, dd, h + 1, w4, hp); \
    } else { zero_row(W[PP][0]); zero_row(W[PP][1]); zero_row(W[PP][2]); } \
    float4 a = make_float4(bias, bias, bias, bias); \
    fma_row(a, W[PM][0], kw[0],  kw[1],  kw[2]); \
    fma_row(a, W[PM][1], kw[3],  kw[4],  kw[5]); \
    fma_row(a, W[PM][2], kw[6],  kw[7],  kw[8]); \
    fma_row(a, W[PC][0], kw[9],  kw[10], kw[11]); \
    fma_row(a, W[PC][1], kw[12], kw[13], kw[14]); \
    fma_row(a, W[PC][2], kw[15], kw[16], kw[17]); \
    fma_row(a, W[PP][0], kw[18], kw[19], kw[20]); \
    fma_row(a, W[PP][1], kw[21], kw[22], kw[23]); \
    fma_row(a, W[PP][2], kw[24], kw[25], kw[26]); \
    if (SILU) { a.x = silu(a.x); a.y = silu(a.y); a.z = silu(a.z); a.w = silu(a.w); } \
    *(float4*)(dst + (size_t)(D) * PLANE + h * DIM + w4) = a; \
  }

  #pragma unroll 1
  for (int db = 0; db < DCHUNK; db += 3) {   // ring indices static per 3-step body
    const int d = d0 + db;
    STEP(d,     2, 0, 1);
    STEP(d + 1, 0, 1, 2);
    STEP(d + 2, 1, 2, 0);
  }
  #undef STEP
}

// ---------------- K4b: in-place 1x1 out_proj + bias + residual ----------------
__global__ __launch_bounds__(256) void k4b_out(const float* __restrict__ x,
    const float* __restrict__ out_w, const float* __restrict__ ob,
    float* __restrict__ out) {
  const int v = blockIdx.x * 256 + threadIdx.x;
  float zv[C];
  #pragma unroll
  for (int c = 0; c < C; ++c) zv[c] = out[(size_t)c * S + v];  // read full column
  for (int o = 0; o < C; ++o) {
    const float4* w4 = (const float4*)(out_w + o * C);         // wave-uniform
    float s0 = 0.f, s1 = 0.f, s2 = 0.f, s3 = 0.f;
    #pragma unroll
    for (int c4 = 0; c4 < C / 4; ++c4) {
      const float4 w = w4[c4];
      s0 += w.x * zv[4 * c4 + 0];
      s1 += w.y * zv[4 * c4 + 1];
      s2 += w.z * zv[4 * c4 + 2];
      s3 += w.w * zv[4 * c4 + 3];
    }
    out[(size_t)o * S + v] = (s0 + s1) + (s2 + s3) + ob[o] + x[(size_t)o * S + v];
  }
}

extern "C" void kernel_launch(void* const* d_in, const int* in_sizes, int n_in,
                              void* d_out, int out_size, void* d_ws, size_t ws_size,
                              hipStream_t stream) {
  const float* x      = (const float*)d_in[0];
  const float* norm_w = (const float*)d_in[1];
  const float* norm_b = (const float*)d_in[2];
  const float* in_w   = (const float*)d_in[3];
  const float* in_b   = (const float*)d_in[4];
  const float* ssm_w  = (const float*)d_in[5];
  const float* ssm_b  = (const float*)d_in[6];
  const float* mam_w  = (const float*)d_in[7];
  const float* mam_b  = (const float*)d_in[8];
  const float* sym_w  = (const float*)d_in[9];
  const float* sym_b  = (const float*)d_in[10];
  const float* out_w  = (const float*)d_in[11];
  const float* out_b  = (const float*)d_in[12];
  float* out = (float*)d_out;

  float* ws    = (float*)d_ws;
  float* xp    = ws;                               // C*S floats (226.5 MB)
  float* t1    = xp + (size_t)C * S;               // HALF*S floats (113.3 MB)
  float* st    = t1 + (size_t)HALF * S;
  float* psum  = st;                               // C*PARTS
  float* psq   = st + C * PARTS;                   // C*PARTS
  float* Wp    = st + 2 * C * PARTS;               // C*C
  float* biasp = Wp + C * C;                       // C

  const dim3 cgrid(DIM / 8, DSPLIT, HALF), cblk(24, 8, 1);

  k1_stats<<<C * PARTS, 256, 0, stream>>>(x, psum, psq);
  k1b_prep<<<1, 64, 0, stream>>>(psum, psq, norm_w, norm_b, in_w, in_b, Wp, biasp);
  k2_inproj<<<S / 256, 256, 0, stream>>>(x, Wp, biasp, xp);
  // x1 half: SiLU(conv_ssm(xp[0:32])) -> t1
  dwconv<true><<<cgrid, cblk, 0, stream>>>(xp, ssm_w, ssm_b, t1);
  // x2 half: SiLU(conv_sym(xp[32:64])) -> z upper half (z lives in d_out)
  dwconv<true><<<cgrid, cblk, 0, stream>>>(xp + (size_t)HALF * S, sym_w, sym_b,
                                           out + (size_t)HALF * S);
  // x1 half: conv_mamba(t1) -> z lower half (no activation)
  dwconv<false><<<cgrid, cblk, 0, stream>>>(t1, mam_w, mam_b, out);
  k4b_out<<<S / 256, 256, 0, stream>>>(x, out_w, out_b, out);
}

// Round 4
// 664.388 us; speedup vs baseline: 3.6652x; 1.1833x over previous
//
#include <hip/hip_runtime.h>

typedef unsigned short u16;
typedef unsigned int u32;
typedef short bf16x8 __attribute__((ext_vector_type(8)));
typedef float f32x4 __attribute__((ext_vector_type(4)));

#define DIM 96
#define PLANE (DIM*DIM)   // 9216
#define S 884736          // 96^3
#define C 64
#define HALF 32
#define PARTS 16
#define EPS 1e-5f
#define DSPLIT 8
#define DCHUNK (DIM/DSPLIT)  // 12

#define MFMA(a,b,c) __builtin_amdgcn_mfma_f32_16x16x32_bf16(a,b,c,0,0,0)

__device__ __forceinline__ u16 f2bf(float f) {          // RNE, finite inputs
  u32 u = __builtin_bit_cast(u32, f);
  return (u16)((u + 0x7FFFu + ((u >> 16) & 1u)) >> 16);
}
__device__ __forceinline__ float bf2f(u16 h) {
  return __builtin_bit_cast(float, (u32)h << 16);
}
__device__ __forceinline__ float silu(float v) { return v / (1.f + __expf(-v)); }

// ---------------- K1: per-channel partial sums (deterministic) ----------------
__global__ __launch_bounds__(256) void k1_stats(const float* __restrict__ x,
                                                float* __restrict__ psum,
                                                float* __restrict__ psq) {
  const int bid = blockIdx.x;              // 0 .. C*PARTS-1
  const int ch = bid / PARTS, part = bid % PARTS;
  const int chunk = S / PARTS;
  const float4* p = (const float4*)(x + (size_t)ch * S + (size_t)part * chunk);
  const int n4 = chunk / 4;
  float s = 0.f, q = 0.f;
  for (int i = threadIdx.x; i < n4; i += 256) {
    float4 v = p[i];
    s += (v.x + v.y) + (v.z + v.w);
    q += (v.x * v.x + v.y * v.y) + (v.z * v.z + v.w * v.w);
  }
  #pragma unroll
  for (int off = 32; off > 0; off >>= 1) {
    s += __shfl_down(s, off);
    q += __shfl_down(q, off);
  }
  __shared__ float ls[4], lq[4];
  const int wid = threadIdx.x >> 6, lane = threadIdx.x & 63;
  if (lane == 0) { ls[wid] = s; lq[wid] = q; }
  __syncthreads();
  if (threadIdx.x == 0) {
    psum[bid] = (ls[0] + ls[1]) + (ls[2] + ls[3]);
    psq[bid]  = (lq[0] + lq[1]) + (lq[2] + lq[3]);
  }
}

// ------ K1b: finalize stats; emit bf16 folded in_proj W, bf16 out_proj W ------
__global__ __launch_bounds__(64) void k1b_prep(const float* __restrict__ psum,
    const float* __restrict__ psq,
    const float* __restrict__ norm_w, const float* __restrict__ norm_b,
    const float* __restrict__ in_w, const float* __restrict__ in_b,
    const float* __restrict__ out_w,
    u16* __restrict__ Wp, float* __restrict__ biasp, u16* __restrict__ Wo) {
  __shared__ float a_s[C], b2_s[C];
  const int t = threadIdx.x;               // 0..63 (output row o)
  float s = 0.f, q = 0.f;
  for (int i = 0; i < PARTS; ++i) { s += psum[t * PARTS + i]; q += psq[t * PARTS + i]; }
  const float inv = 1.f / (float)S;
  const float mu = s * inv;
  const float var = q * inv - mu * mu;
  const float rsig = rsqrtf(var + EPS);
  const float a = norm_w[t] * rsig;
  const float b2 = norm_b[t] - mu * a;
  a_s[t] = a; b2_s[t] = b2;
  __syncthreads();
  float bp = in_b[t];
  for (int c = 0; c < C; ++c) {
    const float w = in_w[t * C + c];
    Wp[t * C + c] = f2bf(w * a_s[c]);      // folded norm scale, row-major [o][c]
    bp += b2_s[c] * w;                     // folded norm shift
    Wo[t * C + c] = f2bf(out_w[t * C + c]);
  }
  biasp[t] = bp;
}

// ---------------- K2: 1x1 in_proj via bf16 MFMA, fp32 x -> bf16 xp ------------
__global__ __launch_bounds__(256) void k2_mfma(const float* __restrict__ x,
    const u16* __restrict__ Wp, const float* __restrict__ biasp,
    u16* __restrict__ xp) {
  const int lane = threadIdx.x & 63, wid = threadIdx.x >> 6;
  const int n = lane & 15, kg = lane >> 4;         // n: M/N row-col, kg: K-group
  bf16x8 A[4][2];                                  // A[m=n][k=kg*8+j], 4 o-tiles
  #pragma unroll
  for (int t = 0; t < 4; ++t)
    #pragma unroll
    for (int h = 0; h < 2; ++h)
      A[t][h] = *(const bf16x8*)(Wp + (t * 16 + n) * C + h * 32 + kg * 8);
  f32x4 bias_v[4];
  #pragma unroll
  for (int t = 0; t < 4; ++t)
    #pragma unroll
    for (int j = 0; j < 4; ++j) bias_v[t][j] = biasp[t * 16 + kg * 4 + j];

  #pragma unroll 1
  for (int it = 0; it < 4; ++it) {
    const int v0 = blockIdx.x * 256 + wid * 64 + it * 16;
    const float* xl = x + v0 + n;
    float f0[8], f1[8];
    #pragma unroll
    for (int j = 0; j < 8; ++j) {
      f0[j] = xl[(size_t)(kg * 8 + j) * S];
      f1[j] = xl[(size_t)(32 + kg * 8 + j) * S];
    }
    union { u16 u[8]; bf16x8 v; } B0, B1;
    #pragma unroll
    for (int j = 0; j < 8; ++j) { B0.u[j] = f2bf(f0[j]); B1.u[j] = f2bf(f1[j]); }
    f32x4 acc[4];
    #pragma unroll
    for (int t = 0; t < 4; ++t) acc[t] = bias_v[t];
    #pragma unroll
    for (int t = 0; t < 4; ++t) {
      acc[t] = MFMA(A[t][0], B0.v, acc[t]);
      acc[t] = MFMA(A[t][1], B1.v, acc[t]);
    }
    u16* xo = xp + v0 + n;
    #pragma unroll
    for (int t = 0; t < 4; ++t)
      #pragma unroll
      for (int j = 0; j < 4; ++j)
        xo[(size_t)(t * 16 + kg * 4 + j) * S] = f2bf(acc[t][j]);
  }
}

// ---------------- sliding-window depthwise 3x3x3, bf16 I/O --------------------
struct Row { float lo; float4 m; float hi; };

__device__ __forceinline__ void zero_row(Row& r) {
  r.lo = 0.f; r.m = make_float4(0.f, 0.f, 0.f, 0.f); r.hi = 0.f;
}

__device__ __forceinline__ void load_row(Row& r, const u16* __restrict__ src,
                                         int dd, int hh, int w4, bool hok) {
  if (hok) {
    const u16* row = src + (size_t)dd * PLANE + hh * DIM;
    r.lo = (w4 > 0) ? bf2f(row[w4 - 1]) : 0.f;
    ushort4 mm = *(const ushort4*)(row + w4);
    r.m = make_float4(bf2f(mm.x), bf2f(mm.y), bf2f(mm.z), bf2f(mm.w));
    r.hi = (w4 < DIM - 4) ? bf2f(row[w4 + 4]) : 0.f;
  } else {
    zero_row(r);
  }
}

__device__ __forceinline__ void fma_row(float4& a, const Row& r,
                                        float t0, float t1, float t2) {
  a.x += t0 * r.lo  + t1 * r.m.x + t2 * r.m.y;
  a.y += t0 * r.m.x + t1 * r.m.y + t2 * r.m.z;
  a.z += t0 * r.m.y + t1 * r.m.z + t2 * r.m.w;
  a.w += t0 * r.m.z + t1 * r.m.w + t2 * r.hi;
}

template<bool SILU>
__global__ __launch_bounds__(192) void dwconv(const u16* __restrict__ src0,
    const float* __restrict__ kw0, const float* __restrict__ b0,
    u16* __restrict__ dst0) {
  const int c = blockIdx.z;
  const u16* src = src0 + (size_t)c * S;
  u16* dst = dst0 + (size_t)c * S;
  const float* kwp = kw0 + c * 27;         // wave-uniform
  float kw[27];
  #pragma unroll
  for (int i = 0; i < 27; ++i) kw[i] = kwp[i];
  const float bias = b0[c];

  const int w4 = threadIdx.x * 4;
  const int h  = blockIdx.x * 8 + threadIdx.y;
  const bool hm = h > 0, hp = h < DIM - 1;
  const int d0 = blockIdx.y * DCHUNK;

  Row W[3][3];                             // [plane ring][kh]
  if (d0 > 0) {
    load_row(W[2][0], src, d0 - 1, h - 1, w4, hm);
    load_row(W[2][1], src, d0 - 1, h,     w4, true);
    load_row(W[2][2], src, d0 - 1, h + 1, w4, hp);
  } else { zero_row(W[2][0]); zero_row(W[2][1]); zero_row(W[2][2]); }
  load_row(W[0][0], src, d0, h - 1, w4, hm);
  load_row(W[0][1], src, d0, h,     w4, true);
  load_row(W[0][2], src, d0, h + 1, w4, hp);

  #define STEP(D, PM, PC, PP) { \
    const int dd = (D) + 1; \
    if (dd < DIM) { \
      load_row(W[PP][0], src, dd, h - 1, w4, hm); \
      load_row(W[PP][1], src, dd, h,     w4, true); \
      load_row(W[PP][2], src, dd, h + 1, w4, hp); \
    } else { zero_row(W[PP][0]); zero_row(W[PP][1]); zero_row(W[PP][2]); } \
    float4 a = make_float4(bias, bias, bias, bias); \
    fma_row(a, W[PM][0], kw[0],  kw[1],  kw[2]); \
    fma_row(a, W[PM][1], kw[3],  kw[4],  kw[5]); \
    fma_row(a, W[PM][2], kw[6],  kw[7],  kw[8]); \
    fma_row(a, W[PC][0], kw[9],  kw[10], kw[11]); \
    fma_row(a, W[PC][1], kw[12], kw[13], kw[14]); \
    fma_row(a, W[PC][2], kw[15], kw[16], kw[17]); \
    fma_row(a, W[PP][0], kw[18], kw[19], kw[20]); \
    fma_row(a, W[PP][1], kw[21], kw[22], kw[23]); \
    fma_row(a, W[PP][2], kw[24], kw[25], kw[26]); \
    if (SILU) { a.x = silu(a.x); a.y = silu(a.y); a.z = silu(a.z); a.w = silu(a.w); } \
    ushort4 o; o.x = f2bf(a.x); o.y = f2bf(a.y); o.z = f2bf(a.z); o.w = f2bf(a.w); \
    *(ushort4*)(dst + (size_t)(D) * PLANE + h * DIM + w4) = o; \
  }

  #pragma unroll 1
  for (int db = 0; db < DCHUNK; db += 3) {
    const int d = d0 + db;
    STEP(d,     2, 0, 1);
    STEP(d + 1, 0, 1, 2);
    STEP(d + 2, 1, 2, 0);
  }
  #undef STEP
}

// --------- K4b: 1x1 out_proj via bf16 MFMA + bias + residual -> fp32 out ------
__global__ __launch_bounds__(256) void k4b_mfma(const u16* __restrict__ z,
    const float* __restrict__ x, const u16* __restrict__ Wo,
    const float* __restrict__ ob, float* __restrict__ out) {
  const int lane = threadIdx.x & 63, wid = threadIdx.x >> 6;
  const int n = lane & 15, kg = lane >> 4;
  bf16x8 A[4][2];
  #pragma unroll
  for (int t = 0; t < 4; ++t)
    #pragma unroll
    for (int h = 0; h < 2; ++h)
      A[t][h] = *(const bf16x8*)(Wo + (t * 16 + n) * C + h * 32 + kg * 8);
  f32x4 bias_v[4];
  #pragma unroll
  for (int t = 0; t < 4; ++t)
    #pragma unroll
    for (int j = 0; j < 4; ++j) bias_v[t][j] = ob[t * 16 + kg * 4 + j];

  #pragma unroll 1
  for (int it = 0; it < 4; ++it) {
    const int v0 = blockIdx.x * 256 + wid * 64 + it * 16;
    const u16* zl = z + v0 + n;
    union { u16 u[8]; bf16x8 v; } B0, B1;
    #pragma unroll
    for (int j = 0; j < 8; ++j) {
      B0.u[j] = zl[(size_t)(kg * 8 + j) * S];
      B1.u[j] = zl[(size_t)(32 + kg * 8 + j) * S];
    }
    f32x4 acc[4];
    #pragma unroll
    for (int t = 0; t < 4; ++t) acc[t] = bias_v[t];
    #pragma unroll
    for (int t = 0; t < 4; ++t) {
      acc[t] = MFMA(A[t][0], B0.v, acc[t]);
      acc[t] = MFMA(A[t][1], B1.v, acc[t]);
    }
    const float* xl = x + v0 + n;
    float* op = out + v0 + n;
    #pragma unroll
    for (int t = 0; t < 4; ++t)
      #pragma unroll
      for (int j = 0; j < 4; ++j)
        op[(size_t)(t * 16 + kg * 4 + j) * S] =
            acc[t][j] + xl[(size_t)(t * 16 + kg * 4 + j) * S];
  }
}

extern "C" void kernel_launch(void* const* d_in, const int* in_sizes, int n_in,
                              void* d_out, int out_size, void* d_ws, size_t ws_size,
                              hipStream_t stream) {
  const float* x      = (const float*)d_in[0];
  const float* norm_w = (const float*)d_in[1];
  const float* norm_b = (const float*)d_in[2];
  const float* in_w   = (const float*)d_in[3];
  const float* in_b   = (const float*)d_in[4];
  const float* ssm_w  = (const float*)d_in[5];
  const float* ssm_b  = (const float*)d_in[6];
  const float* mam_w  = (const float*)d_in[7];
  const float* mam_b  = (const float*)d_in[8];
  const float* sym_w  = (const float*)d_in[9];
  const float* sym_b  = (const float*)d_in[10];
  const float* out_w  = (const float*)d_in[11];
  const float* out_b  = (const float*)d_in[12];
  float* out = (float*)d_out;

  u16* xp = (u16*)d_ws;                        // C*S bf16  (113.2 MB)
  u16* t1 = xp + (size_t)C * S;                // HALF*S bf16 (56.6 MB)
  u16* z  = t1 + (size_t)HALF * S;             // C*S bf16  (113.2 MB)
  float* psum  = (float*)(z + (size_t)C * S);  // C*PARTS
  float* psq   = psum + C * PARTS;             // C*PARTS
  u16* Wp      = (u16*)(psq + C * PARTS);      // C*C bf16
  u16* Wo      = Wp + C * C;                   // C*C bf16
  float* biasp = (float*)(Wo + C * C);         // C fp32

  const dim3 cgrid(DIM / 8, DSPLIT, HALF), cblk(24, 8, 1);

  k1_stats<<<C * PARTS, 256, 0, stream>>>(x, psum, psq);
  k1b_prep<<<1, 64, 0, stream>>>(psum, psq, norm_w, norm_b, in_w, in_b, out_w,
                                 Wp, biasp, Wo);
  k2_mfma<<<S / 256, 256, 0, stream>>>(x, Wp, biasp, xp);
  // x1 half: SiLU(conv_ssm(xp[0:32])) -> t1
  dwconv<true><<<cgrid, cblk, 0, stream>>>(xp, ssm_w, ssm_b, t1);
  // x2 half: SiLU(conv_sym(xp[32:64])) -> z upper half
  dwconv<true><<<cgrid, cblk, 0, stream>>>(xp + (size_t)HALF * S, sym_w, sym_b,
                                           z + (size_t)HALF * S);
  // x1 half: conv_mamba(t1) -> z lower half (no activation)
  dwconv<false><<<cgrid, cblk, 0, stream>>>(t1, mam_w, mam_b, z);
  k4b_mfma<<<S / 256, 256, 0, stream>>>(z, x, Wo, out_b, out);
}

// Round 5
// 524.495 us; speedup vs baseline: 4.6428x; 1.2667x over previous
//
#include <hip/hip_runtime.h>

typedef unsigned short u16;
typedef unsigned int u32;
typedef short bf16x8 __attribute__((ext_vector_type(8)));
typedef float f32x16 __attribute__((ext_vector_type(16)));
typedef u16 u16x8 __attribute__((ext_vector_type(8)));

#define DIM 96
#define PLANE (DIM*DIM)   // 9216
#define S 884736          // 96^3
#define C 64
#define HALF 32
#define PARTS 16
#define EPS 1e-5f
#define DSPLIT 8
#define DCHUNK (DIM/DSPLIT)  // 12, divisible by 3 (ring rotation static)

#define MFMA32(a,b,c) __builtin_amdgcn_mfma_f32_32x32x16_bf16(a,b,c,0,0,0)

__device__ __forceinline__ u16 f2bf(float f) {          // RNE, finite inputs
  u32 u = __builtin_bit_cast(u32, f);
  return (u16)((u + 0x7FFFu + ((u >> 16) & 1u)) >> 16);
}
__device__ __forceinline__ float bf2f(u16 h) {
  return __builtin_bit_cast(float, (u32)h << 16);
}
__device__ __forceinline__ float silu(float v) { return v / (1.f + __expf(-v)); }

// ---------------- K1: per-channel partial sums (deterministic) ----------------
__global__ __launch_bounds__(256) void k1_stats(const float* __restrict__ x,
                                                float* __restrict__ psum,
                                                float* __restrict__ psq) {
  const int bid = blockIdx.x;              // 0 .. C*PARTS-1
  const int ch = bid / PARTS, part = bid % PARTS;
  const int chunk = S / PARTS;
  const float4* p = (const float4*)(x + (size_t)ch * S + (size_t)part * chunk);
  const int n4 = chunk / 4;
  float s = 0.f, q = 0.f;
  for (int i = threadIdx.x; i < n4; i += 256) {
    float4 v = p[i];
    s += (v.x + v.y) + (v.z + v.w);
    q += (v.x * v.x + v.y * v.y) + (v.z * v.z + v.w * v.w);
  }
  #pragma unroll
  for (int off = 32; off > 0; off >>= 1) {
    s += __shfl_down(s, off);
    q += __shfl_down(q, off);
  }
  __shared__ float ls[4], lq[4];
  const int wid = threadIdx.x >> 6, lane = threadIdx.x & 63;
  if (lane == 0) { ls[wid] = s; lq[wid] = q; }
  __syncthreads();
  if (threadIdx.x == 0) {
    psum[bid] = (ls[0] + ls[1]) + (ls[2] + ls[3]);
    psq[bid]  = (lq[0] + lq[1]) + (lq[2] + lq[3]);
  }
}

// ------ K1b: finalize stats; emit bf16 folded in_proj W, bf16 out_proj W ------
__global__ __launch_bounds__(64) void k1b_prep(const float* __restrict__ psum,
    const float* __restrict__ psq,
    const float* __restrict__ norm_w, const float* __restrict__ norm_b,
    const float* __restrict__ in_w, const float* __restrict__ in_b,
    const float* __restrict__ out_w,
    u16* __restrict__ Wp, float* __restrict__ biasp, u16* __restrict__ Wo) {
  __shared__ float a_s[C], b2_s[C];
  const int t = threadIdx.x;               // 0..63 (output row o)
  float s = 0.f, q = 0.f;
  for (int i = 0; i < PARTS; ++i) { s += psum[t * PARTS + i]; q += psq[t * PARTS + i]; }
  const float inv = 1.f / (float)S;
  const float mu = s * inv;
  const float var = q * inv - mu * mu;
  const float rsig = rsqrtf(var + EPS);
  const float a = norm_w[t] * rsig;
  const float b2 = norm_b[t] - mu * a;
  a_s[t] = a; b2_s[t] = b2;
  __syncthreads();
  float bp = in_b[t];
  for (int c = 0; c < C; ++c) {
    const float w = in_w[t * C + c];
    Wp[t * C + c] = f2bf(w * a_s[c]);      // folded norm scale, row-major [o][c]
    bp += b2_s[c] * w;                     // folded norm shift
    Wo[t * C + c] = f2bf(out_w[t * C + c]);
  }
  biasp[t] = bp;
}

// ------ K2: 1x1 in_proj, 32x32x16 MFMA, even/odd interleaved voxel tiles ------
__global__ __launch_bounds__(256) void k2_mfma(const float* __restrict__ x,
    const u16* __restrict__ Wp, const float* __restrict__ biasp,
    u16* __restrict__ xp) {
  const int lane = threadIdx.x & 63, wid = threadIdx.x >> 6;
  const int n = lane & 31, hf = lane >> 5;
  const int v0 = blockIdx.x * 256 + wid * 64;      // 64 voxels per wave
  bf16x8 A[2][4];                                  // [o-tile][k-slice]
  #pragma unroll
  for (int t = 0; t < 2; ++t)
    #pragma unroll
    for (int s = 0; s < 4; ++s)
      A[t][s] = *(const bf16x8*)(Wp + (t * 32 + n) * C + s * 16 + hf * 8);

  f32x16 accE[2], accO[2];
  #pragma unroll
  for (int t = 0; t < 2; ++t)
    #pragma unroll
    for (int r = 0; r < 16; ++r) {
      const float b = biasp[t * 32 + (r & 3) + 8 * (r >> 2) + 4 * hf];
      accE[t][r] = b; accO[t][r] = b;
    }

  #pragma unroll
  for (int s = 0; s < 4; ++s) {
    union { u16 u[8]; bf16x8 v; } BE, BO;
    #pragma unroll
    for (int j = 0; j < 8; ++j) {
      const float2 xv = *(const float2*)(x + (size_t)(s * 16 + hf * 8 + j) * S + v0 + 2 * n);
      BE.u[j] = f2bf(xv.x); BO.u[j] = f2bf(xv.y);
    }
    #pragma unroll
    for (int t = 0; t < 2; ++t) {
      accE[t] = MFMA32(A[t][s], BE.v, accE[t]);
      accO[t] = MFMA32(A[t][s], BO.v, accO[t]);
    }
  }
  #pragma unroll
  for (int t = 0; t < 2; ++t)
    #pragma unroll
    for (int r = 0; r < 16; ++r) {
      const int o = t * 32 + (r & 3) + 8 * (r >> 2) + 4 * hf;
      ushort2 pr; pr.x = f2bf(accE[t][r]); pr.y = f2bf(accO[t][r]);
      *(ushort2*)(xp + (size_t)o * S + v0 + 2 * n) = pr;
    }
}

// ---------------- sliding-window depthwise 3x3x3, bf16 I/O, 8-wide ------------
__device__ __forceinline__ void zero_row8(float* __restrict__ r) {
  #pragma unroll
  for (int i = 0; i < 10; ++i) r[i] = 0.f;
}

__device__ __forceinline__ void load_row8(float* __restrict__ r,
    const u16* __restrict__ src, int dd, int hh, int w8, bool hok) {
  if (hok) {
    const u16* row = src + (size_t)dd * PLANE + hh * DIM + w8;
    r[0] = (w8 > 0) ? bf2f(row[-1]) : 0.f;
    const u16x8 v = *(const u16x8*)row;
    #pragma unroll
    for (int i = 0; i < 8; ++i) r[1 + i] = bf2f(v[i]);
    r[9] = (w8 < DIM - 8) ? bf2f(row[8]) : 0.f;
  } else {
    zero_row8(r);
  }
}

__device__ __forceinline__ void fma_row8(float* __restrict__ a,
    const float* __restrict__ r, float t0, float t1, float t2) {
  #pragma unroll
  for (int i = 0; i < 8; ++i) a[i] += t0 * r[i] + t1 * r[i + 1] + t2 * r[i + 2];
}

template<bool SILU>
__global__ __launch_bounds__(192) void dwconv(const u16* __restrict__ src0,
    const float* __restrict__ kw0, const float* __restrict__ b0,
    u16* __restrict__ dst0) {
  const int c = blockIdx.z;
  const u16* src = src0 + (size_t)c * S;
  u16* dst = dst0 + (size_t)c * S;
  const float* kwp = kw0 + c * 27;         // wave-uniform
  float kw[27];
  #pragma unroll
  for (int i = 0; i < 27; ++i) kw[i] = kwp[i];
  const float bias = b0[c];

  const int w8 = threadIdx.x * 8;
  const int h  = blockIdx.x * 16 + threadIdx.y;
  const bool hm = h > 0, hp = h < DIM - 1;
  const int d0 = blockIdx.y * DCHUNK;

  float W[3][3][10];                       // [plane ring][kh][w-window]
  if (d0 > 0) {
    load_row8(W[2][0], src, d0 - 1, h - 1, w8, hm);
    load_row8(W[2][1], src, d0 - 1, h,     w8, true);
    load_row8(W[2][2], src, d0 - 1, h + 1, w8, hp);
  } else { zero_row8(W[2][0]); zero_row8(W[2][1]); zero_row8(W[2][2]); }
  load_row8(W[0][0], src, d0, h - 1, w8, hm);
  load_row8(W[0][1], src, d0, h,     w8, true);
  load_row8(W[0][2], src, d0, h + 1, w8, hp);

  #define STEP(D, PM, PC, PP) { \
    const int dd = (D) + 1; \
    if (dd < DIM) { \
      load_row8(W[PP][0], src, dd, h - 1, w8, hm); \
      load_row8(W[PP][1], src, dd, h,     w8, true); \
      load_row8(W[PP][2], src, dd, h + 1, w8, hp); \
    } else { zero_row8(W[PP][0]); zero_row8(W[PP][1]); zero_row8(W[PP][2]); } \
    float a[8]; \
    _Pragma("unroll") \
    for (int i = 0; i < 8; ++i) a[i] = bias; \
    fma_row8(a, W[PM][0], kw[0],  kw[1],  kw[2]); \
    fma_row8(a, W[PM][1], kw[3],  kw[4],  kw[5]); \
    fma_row8(a, W[PM][2], kw[6],  kw[7],  kw[8]); \
    fma_row8(a, W[PC][0], kw[9],  kw[10], kw[11]); \
    fma_row8(a, W[PC][1], kw[12], kw[13], kw[14]); \
    fma_row8(a, W[PC][2], kw[15], kw[16], kw[17]); \
    fma_row8(a, W[PP][0], kw[18], kw[19], kw[20]); \
    fma_row8(a, W[PP][1], kw[21], kw[22], kw[23]); \
    fma_row8(a, W[PP][2], kw[24], kw[25], kw[26]); \
    u16x8 o; \
    _Pragma("unroll") \
    for (int i = 0; i < 8; ++i) { \
      float v = a[i]; \
      if (SILU) v = silu(v); \
      o[i] = f2bf(v); \
    } \
    *(u16x8*)(dst + (size_t)(D) * PLANE + h * DIM + w8) = o; \
  }

  #pragma unroll 1
  for (int db = 0; db < DCHUNK; db += 3) {   // ring indices static per 3-step body
    const int d = d0 + db;
    STEP(d,     2, 0, 1);
    STEP(d + 1, 0, 1, 2);
    STEP(d + 2, 1, 2, 0);
  }
  #undef STEP
}

// --- K4b: 1x1 out_proj (32x32x16 MFMA) + bias + residual, even/odd tiles ------
__global__ __launch_bounds__(256) void k4b_mfma(const u16* __restrict__ z,
    const float* __restrict__ x, const u16* __restrict__ Wo,
    const float* __restrict__ ob, float* __restrict__ out) {
  const int lane = threadIdx.x & 63, wid = threadIdx.x >> 6;
  const int n = lane & 31, hf = lane >> 5;
  const int v0 = blockIdx.x * 256 + wid * 64;
  bf16x8 A[2][4];
  #pragma unroll
  for (int t = 0; t < 2; ++t)
    #pragma unroll
    for (int s = 0; s < 4; ++s)
      A[t][s] = *(const bf16x8*)(Wo + (t * 32 + n) * C + s * 16 + hf * 8);

  f32x16 accE[2], accO[2];
  #pragma unroll
  for (int t = 0; t < 2; ++t)
    #pragma unroll
    for (int r = 0; r < 16; ++r) {
      const float b = ob[t * 32 + (r & 3) + 8 * (r >> 2) + 4 * hf];
      accE[t][r] = b; accO[t][r] = b;
    }

  #pragma unroll
  for (int s = 0; s < 4; ++s) {
    union { u16 u[8]; bf16x8 v; } BE, BO;
    #pragma unroll
    for (int j = 0; j < 8; ++j) {
      const u32 zv = *(const u32*)(z + (size_t)(s * 16 + hf * 8 + j) * S + v0 + 2 * n);
      BE.u[j] = (u16)(zv & 0xFFFFu); BO.u[j] = (u16)(zv >> 16);
    }
    #pragma unroll
    for (int t = 0; t < 2; ++t) {
      accE[t] = MFMA32(A[t][s], BE.v, accE[t]);
      accO[t] = MFMA32(A[t][s], BO.v, accO[t]);
    }
  }
  #pragma unroll
  for (int t = 0; t < 2; ++t)
    #pragma unroll
    for (int r = 0; r < 16; ++r) {
      const int o = t * 32 + (r & 3) + 8 * (r >> 2) + 4 * hf;
      const float2 xr = *(const float2*)(x + (size_t)o * S + v0 + 2 * n);
      float2 ov; ov.x = accE[t][r] + xr.x; ov.y = accO[t][r] + xr.y;
      *(float2*)(out + (size_t)o * S + v0 + 2 * n) = ov;
    }
}

extern "C" void kernel_launch(void* const* d_in, const int* in_sizes, int n_in,
                              void* d_out, int out_size, void* d_ws, size_t ws_size,
                              hipStream_t stream) {
  const float* x      = (const float*)d_in[0];
  const float* norm_w = (const float*)d_in[1];
  const float* norm_b = (const float*)d_in[2];
  const float* in_w   = (const float*)d_in[3];
  const float* in_b   = (const float*)d_in[4];
  const float* ssm_w  = (const float*)d_in[5];
  const float* ssm_b  = (const float*)d_in[6];
  const float* mam_w  = (const float*)d_in[7];
  const float* mam_b  = (const float*)d_in[8];
  const float* sym_w  = (const float*)d_in[9];
  const float* sym_b  = (const float*)d_in[10];
  const float* out_w  = (const float*)d_in[11];
  const float* out_b  = (const float*)d_in[12];
  float* out = (float*)d_out;

  u16* xp = (u16*)d_ws;                        // C*S bf16  (113.2 MB)
  u16* t1 = xp + (size_t)C * S;                // HALF*S bf16 (56.6 MB)
  u16* z  = t1 + (size_t)HALF * S;             // C*S bf16  (113.2 MB)
  float* psum  = (float*)(z + (size_t)C * S);  // C*PARTS
  float* psq   = psum + C * PARTS;             // C*PARTS
  u16* Wp      = (u16*)(psq + C * PARTS);      // C*C bf16
  u16* Wo      = Wp + C * C;                   // C*C bf16
  float* biasp = (float*)(Wo + C * C);         // C fp32

  const dim3 cgrid(DIM / 16, DSPLIT, HALF), cblk(12, 16, 1);

  k1_stats<<<C * PARTS, 256, 0, stream>>>(x, psum, psq);
  k1b_prep<<<1, 64, 0, stream>>>(psum, psq, norm_w, norm_b, in_w, in_b, out_w,
                                 Wp, biasp, Wo);
  k2_mfma<<<S / 256, 256, 0, stream>>>(x, Wp, biasp, xp);
  // x1 half: SiLU(conv_ssm(xp[0:32])) -> t1
  dwconv<true><<<cgrid, cblk, 0, stream>>>(xp, ssm_w, ssm_b, t1);
  // x2 half: SiLU(conv_sym(xp[32:64])) -> z upper half
  dwconv<true><<<cgrid, cblk, 0, stream>>>(xp + (size_t)HALF * S, sym_w, sym_b,
                                           z + (size_t)HALF * S);
  // x1 half: conv_mamba(t1) -> z lower half (no activation)
  dwconv<false><<<cgrid, cblk, 0, stream>>>(t1, mam_w, mam_b, z);
  k4b_mfma<<<S / 256, 256, 0, stream>>>(z, x, Wo, out_b, out);
}

// Round 6
// 506.156 us; speedup vs baseline: 4.8110x; 1.0362x over previous
//
#include <hip/hip_runtime.h>

typedef unsigned short u16;
typedef unsigned int u32;
typedef short bf16x8 __attribute__((ext_vector_type(8)));
typedef float f32x16 __attribute__((ext_vector_type(16)));
typedef u16 u16x8 __attribute__((ext_vector_type(8)));

#define DIM 96
#define PLANE (DIM*DIM)   // 9216
#define S 884736          // 96^3
#define C 64
#define HALF 32
#define PARTS 16
#define EPS 1e-5f
#define DSPLIT 8
#define DCHUNK (DIM/DSPLIT)  // 12, divisible by 3 (ring rotation static)

#define MFMA32(a,b,c) __builtin_amdgcn_mfma_f32_32x32x16_bf16(a,b,c,0,0,0)

__device__ __forceinline__ u16 f2bf(float f) {          // RNE, finite inputs
  u32 u = __builtin_bit_cast(u32, f);
  return (u16)((u + 0x7FFFu + ((u >> 16) & 1u)) >> 16);
}
__device__ __forceinline__ float bf2f(u16 h) {
  return __builtin_bit_cast(float, (u32)h << 16);
}
__device__ __forceinline__ float silu(float v) { return v / (1.f + __expf(-v)); }

// ---- K1: per-channel partial sums (deterministic) + bf16 copy of x -----------
__global__ __launch_bounds__(256) void k1_stats(const float* __restrict__ x,
                                                u16* __restrict__ xb,
                                                float* __restrict__ psum,
                                                float* __restrict__ psq) {
  const int bid = blockIdx.x;              // 0 .. C*PARTS-1
  const int ch = bid / PARTS, part = bid % PARTS;
  const int chunk = S / PARTS;
  const size_t base = (size_t)ch * S + (size_t)part * chunk;
  const float4* p = (const float4*)(x + base);
  ushort4* xb4 = (ushort4*)(xb + base);
  const int n4 = chunk / 4;
  float s = 0.f, q = 0.f;
  for (int i = threadIdx.x; i < n4; i += 256) {
    float4 v = p[i];
    s += (v.x + v.y) + (v.z + v.w);
    q += (v.x * v.x + v.y * v.y) + (v.z * v.z + v.w * v.w);
    ushort4 o; o.x = f2bf(v.x); o.y = f2bf(v.y); o.z = f2bf(v.z); o.w = f2bf(v.w);
    xb4[i] = o;
  }
  #pragma unroll
  for (int off = 32; off > 0; off >>= 1) {
    s += __shfl_down(s, off);
    q += __shfl_down(q, off);
  }
  __shared__ float ls[4], lq[4];
  const int wid = threadIdx.x >> 6, lane = threadIdx.x & 63;
  if (lane == 0) { ls[wid] = s; lq[wid] = q; }
  __syncthreads();
  if (threadIdx.x == 0) {
    psum[bid] = (ls[0] + ls[1]) + (ls[2] + ls[3]);
    psq[bid]  = (lq[0] + lq[1]) + (lq[2] + lq[3]);
  }
}

// ------ K1b: finalize stats; emit bf16 folded in_proj W, bf16 out_proj W ------
__global__ __launch_bounds__(64) void k1b_prep(const float* __restrict__ psum,
    const float* __restrict__ psq,
    const float* __restrict__ norm_w, const float* __restrict__ norm_b,
    const float* __restrict__ in_w, const float* __restrict__ in_b,
    const float* __restrict__ out_w,
    u16* __restrict__ Wp, float* __restrict__ biasp, u16* __restrict__ Wo) {
  __shared__ float a_s[C], b2_s[C];
  const int t = threadIdx.x;               // 0..63 (output row o)
  float s = 0.f, q = 0.f;
  for (int i = 0; i < PARTS; ++i) { s += psum[t * PARTS + i]; q += psq[t * PARTS + i]; }
  const float inv = 1.f / (float)S;
  const float mu = s * inv;
  const float var = q * inv - mu * mu;
  const float rsig = rsqrtf(var + EPS);
  const float a = norm_w[t] * rsig;
  const float b2 = norm_b[t] - mu * a;
  a_s[t] = a; b2_s[t] = b2;
  __syncthreads();
  float bp = in_b[t];
  for (int c = 0; c < C; ++c) {
    const float w = in_w[t * C + c];
    Wp[t * C + c] = f2bf(w * a_s[c]);      // folded norm scale, row-major [o][c]
    bp += b2_s[c] * w;                     // folded norm shift
    Wo[t * C + c] = f2bf(out_w[t * C + c]);
  }
  biasp[t] = bp;
}

// ------ K2: 1x1 in_proj, 32x32x16 MFMA, even/odd interleaved voxel tiles ------
__global__ __launch_bounds__(256) void k2_mfma(const u16* __restrict__ xb,
    const u16* __restrict__ Wp, const float* __restrict__ biasp,
    u16* __restrict__ xp) {
  const int lane = threadIdx.x & 63, wid = threadIdx.x >> 6;
  const int n = lane & 31, hf = lane >> 5;
  const int v0 = blockIdx.x * 256 + wid * 64;      // 64 voxels per wave
  bf16x8 A[2][4];                                  // [o-tile][k-slice]
  #pragma unroll
  for (int t = 0; t < 2; ++t)
    #pragma unroll
    for (int s = 0; s < 4; ++s)
      A[t][s] = *(const bf16x8*)(Wp + (t * 32 + n) * C + s * 16 + hf * 8);

  f32x16 accE[2], accO[2];
  #pragma unroll
  for (int t = 0; t < 2; ++t)
    #pragma unroll
    for (int r = 0; r < 16; ++r) {
      const float b = biasp[t * 32 + (r & 3) + 8 * (r >> 2) + 4 * hf];
      accE[t][r] = b; accO[t][r] = b;
    }

  #pragma unroll
  for (int s = 0; s < 4; ++s) {
    union { u16 u[8]; bf16x8 v; } BE, BO;
    #pragma unroll
    for (int j = 0; j < 8; ++j) {
      const u32 xv = *(const u32*)(xb + (size_t)(s * 16 + hf * 8 + j) * S + v0 + 2 * n);
      BE.u[j] = (u16)(xv & 0xFFFFu); BO.u[j] = (u16)(xv >> 16);
    }
    #pragma unroll
    for (int t = 0; t < 2; ++t) {
      accE[t] = MFMA32(A[t][s], BE.v, accE[t]);
      accO[t] = MFMA32(A[t][s], BO.v, accO[t]);
    }
  }
  #pragma unroll
  for (int t = 0; t < 2; ++t)
    #pragma unroll
    for (int r = 0; r < 16; ++r) {
      const int o = t * 32 + (r & 3) + 8 * (r >> 2) + 4 * hf;
      ushort2 pr; pr.x = f2bf(accE[t][r]); pr.y = f2bf(accO[t][r]);
      *(ushort2*)(xp + (size_t)o * S + v0 + 2 * n) = pr;
    }
}

// ---------------- sliding-window depthwise 3x3x3, bf16 I/O, 8-wide ------------
__device__ __forceinline__ void zero_row8(float* __restrict__ r) {
  #pragma unroll
  for (int i = 0; i < 10; ++i) r[i] = 0.f;
}

__device__ __forceinline__ void load_row8(float* __restrict__ r,
    const u16* __restrict__ src, int dd, int hh, int w8, bool hok) {
  if (hok) {
    const u16* row = src + (size_t)dd * PLANE + hh * DIM + w8;
    r[0] = (w8 > 0) ? bf2f(row[-1]) : 0.f;
    const u16x8 v = *(const u16x8*)row;
    #pragma unroll
    for (int i = 0; i < 8; ++i) r[1 + i] = bf2f(v[i]);
    r[9] = (w8 < DIM - 8) ? bf2f(row[8]) : 0.f;
  } else {
    zero_row8(r);
  }
}

__device__ __forceinline__ void fma_row8(float* __restrict__ a,
    const float* __restrict__ r, float t0, float t1, float t2) {
  #pragma unroll
  for (int i = 0; i < 8; ++i) a[i] += t0 * r[i] + t1 * r[i + 1] + t2 * r[i + 2];
}

// convA: c<32: t1[c] = SiLU(conv_ssm(xp[c])); c>=32: z_hi[c-32] = SiLU(conv_sym(xp[c]))
// convB: z_lo[c] = conv_mamba(t1[c])
template<bool SILU>
__global__ __launch_bounds__(192) void dwconv(const u16* __restrict__ srcA,
    const float* __restrict__ kwA, const float* __restrict__ bA,
    u16* __restrict__ dstA,
    const float* __restrict__ kwB, const float* __restrict__ bB,
    u16* __restrict__ dstB) {
  const int c = blockIdx.z;
  const u16* src = srcA + (size_t)c * S;
  u16* dst; const float* kwp; float bias;
  if (c < HALF) { dst = dstA + (size_t)c * S;        kwp = kwA + c * 27;          bias = bA[c]; }
  else          { dst = dstB + (size_t)(c - HALF) * S; kwp = kwB + (c - HALF) * 27; bias = bB[c - HALF]; }
  float kw[27];
  #pragma unroll
  for (int i = 0; i < 27; ++i) kw[i] = kwp[i];

  const int w8 = threadIdx.x * 8;
  const int h  = blockIdx.x * 16 + threadIdx.y;
  const bool hm = h > 0, hp = h < DIM - 1;
  const int d0 = blockIdx.y * DCHUNK;

  float W[3][3][10];                       // [plane ring][kh][w-window]
  if (d0 > 0) {
    load_row8(W[2][0], src, d0 - 1, h - 1, w8, hm);
    load_row8(W[2][1], src, d0 - 1, h,     w8, true);
    load_row8(W[2][2], src, d0 - 1, h + 1, w8, hp);
  } else { zero_row8(W[2][0]); zero_row8(W[2][1]); zero_row8(W[2][2]); }
  load_row8(W[0][0], src, d0, h - 1, w8, hm);
  load_row8(W[0][1], src, d0, h,     w8, true);
  load_row8(W[0][2], src, d0, h + 1, w8, hp);

  #define STEP(D, PM, PC, PP) { \
    const int dd = (D) + 1; \
    if (dd < DIM) { \
      load_row8(W[PP][0], src, dd, h - 1, w8, hm); \
      load_row8(W[PP][1], src, dd, h,     w8, true); \
      load_row8(W[PP][2], src, dd, h + 1, w8, hp); \
    } else { zero_row8(W[PP][0]); zero_row8(W[PP][1]); zero_row8(W[PP][2]); } \
    float a[8]; \
    _Pragma("unroll") \
    for (int i = 0; i < 8; ++i) a[i] = bias; \
    fma_row8(a, W[PM][0], kw[0],  kw[1],  kw[2]); \
    fma_row8(a, W[PM][1], kw[3],  kw[4],  kw[5]); \
    fma_row8(a, W[PM][2], kw[6],  kw[7],  kw[8]); \
    fma_row8(a, W[PC][0], kw[9],  kw[10], kw[11]); \
    fma_row8(a, W[PC][1], kw[12], kw[13], kw[14]); \
    fma_row8(a, W[PC][2], kw[15], kw[16], kw[17]); \
    fma_row8(a, W[PP][0], kw[18], kw[19], kw[20]); \
    fma_row8(a, W[PP][1], kw[21], kw[22], kw[23]); \
    fma_row8(a, W[PP][2], kw[24], kw[25], kw[26]); \
    u16x8 o; \
    _Pragma("unroll") \
    for (int i = 0; i < 8; ++i) { \
      float v = a[i]; \
      if (SILU) v = silu(v); \
      o[i] = f2bf(v); \
    } \
    *(u16x8*)(dst + (size_t)(D) * PLANE + h * DIM + w8) = o; \
  }

  #pragma unroll 1
  for (int db = 0; db < DCHUNK; db += 3) {   // ring indices static per 3-step body
    const int d = d0 + db;
    STEP(d,     2, 0, 1);
    STEP(d + 1, 0, 1, 2);
    STEP(d + 2, 1, 2, 0);
  }
  #undef STEP
}

// --- K4b: 1x1 out_proj (32x32x16 MFMA) + bias + bf16 residual -> fp32 out -----
__global__ __launch_bounds__(256) void k4b_mfma(const u16* __restrict__ z_lo,
    const u16* __restrict__ z_hi, const u16* __restrict__ xb,
    const u16* __restrict__ Wo, const float* __restrict__ ob,
    float* __restrict__ out) {
  const int lane = threadIdx.x & 63, wid = threadIdx.x >> 6;
  const int n = lane & 31, hf = lane >> 5;
  const int v0 = blockIdx.x * 256 + wid * 64;
  bf16x8 A[2][4];
  #pragma unroll
  for (int t = 0; t < 2; ++t)
    #pragma unroll
    for (int s = 0; s < 4; ++s)
      A[t][s] = *(const bf16x8*)(Wo + (t * 32 + n) * C + s * 16 + hf * 8);

  f32x16 accE[2], accO[2];
  #pragma unroll
  for (int t = 0; t < 2; ++t)
    #pragma unroll
    for (int r = 0; r < 16; ++r) {
      const float b = ob[t * 32 + (r & 3) + 8 * (r >> 2) + 4 * hf];
      accE[t][r] = b; accO[t][r] = b;
    }

  #pragma unroll
  for (int s = 0; s < 4; ++s) {
    const u16* zbase = (s < 2) ? z_lo + (size_t)(s * 16) * S
                               : z_hi + (size_t)((s - 2) * 16) * S;
    union { u16 u[8]; bf16x8 v; } BE, BO;
    #pragma unroll
    for (int j = 0; j < 8; ++j) {
      const u32 zv = *(const u32*)(zbase + (size_t)(hf * 8 + j) * S + v0 + 2 * n);
      BE.u[j] = (u16)(zv & 0xFFFFu); BO.u[j] = (u16)(zv >> 16);
    }
    #pragma unroll
    for (int t = 0; t < 2; ++t) {
      accE[t] = MFMA32(A[t][s], BE.v, accE[t]);
      accO[t] = MFMA32(A[t][s], BO.v, accO[t]);
    }
  }
  #pragma unroll
  for (int t = 0; t < 2; ++t)
    #pragma unroll
    for (int r = 0; r < 16; ++r) {
      const int o = t * 32 + (r & 3) + 8 * (r >> 2) + 4 * hf;
      const u32 xr = *(const u32*)(xb + (size_t)o * S + v0 + 2 * n);
      float2 ov;
      ov.x = accE[t][r] + bf2f((u16)(xr & 0xFFFFu));
      ov.y = accO[t][r] + bf2f((u16)(xr >> 16));
      *(float2*)(out + (size_t)o * S + v0 + 2 * n) = ov;
    }
}

extern "C" void kernel_launch(void* const* d_in, const int* in_sizes, int n_in,
                              void* d_out, int out_size, void* d_ws, size_t ws_size,
                              hipStream_t stream) {
  const float* x      = (const float*)d_in[0];
  const float* norm_w = (const float*)d_in[1];
  const float* norm_b = (const float*)d_in[2];
  const float* in_w   = (const float*)d_in[3];
  const float* in_b   = (const float*)d_in[4];
  const float* ssm_w  = (const float*)d_in[5];
  const float* ssm_b  = (const float*)d_in[6];
  const float* mam_w  = (const float*)d_in[7];
  const float* mam_b  = (const float*)d_in[8];
  const float* sym_w  = (const float*)d_in[9];
  const float* sym_b  = (const float*)d_in[10];
  const float* out_w  = (const float*)d_in[11];
  const float* out_b  = (const float*)d_in[12];
  float* out = (float*)d_out;

  // Workspace (u16 units). z_lo ALIASES xp[0:32] (dead after convA; convB is
  // launched after convA completes, stream-ordered). Total ~340 MB.
  u16* xb   = (u16*)d_ws;                      // C*S bf16 copy of x (113.2 MB)
  u16* xp   = xb + (size_t)C * S;              // C*S bf16 (113.2 MB)
  u16* t1   = xp + (size_t)C * S;              // HALF*S bf16 (56.6 MB)
  u16* z_hi = t1 + (size_t)HALF * S;           // HALF*S bf16 (56.6 MB)
  u16* z_lo = xp;                              // alias, HALF*S
  float* psum  = (float*)(z_hi + (size_t)HALF * S);  // C*PARTS
  float* psq   = psum + C * PARTS;             // C*PARTS
  u16* Wp      = (u16*)(psq + C * PARTS);      // C*C bf16
  u16* Wo      = Wp + C * C;                   // C*C bf16
  float* biasp = (float*)(Wo + C * C);         // C fp32

  k1_stats<<<C * PARTS, 256, 0, stream>>>(x, xb, psum, psq);
  k1b_prep<<<1, 64, 0, stream>>>(psum, psq, norm_w, norm_b, in_w, in_b, out_w,
                                 Wp, biasp, Wo);
  k2_mfma<<<S / 256, 256, 0, stream>>>(xb, Wp, biasp, xp);
  // convA: ssm on xp[0:32] -> t1 ; sym on xp[32:64] -> z_hi (both SiLU)
  dwconv<true><<<dim3(DIM / 16, DSPLIT, C), dim3(12, 16, 1), 0, stream>>>(
      xp, ssm_w, ssm_b, t1, sym_w, sym_b, z_hi);
  // convB: mamba on t1 -> z_lo (no activation)
  dwconv<false><<<dim3(DIM / 16, DSPLIT, HALF), dim3(12, 16, 1), 0, stream>>>(
      t1, mam_w, mam_b, z_lo, mam_w, mam_b, z_lo);
  k4b_mfma<<<S / 256, 256, 0, stream>>>(z_lo, z_hi, xb, Wo, out_b, out);
}

// Round 7
// 395.141 us; speedup vs baseline: 6.1627x; 1.2809x over previous
//
#include <hip/hip_runtime.h>

typedef unsigned short u16;
typedef unsigned int u32;
typedef short bf16x8 __attribute__((ext_vector_type(8)));
typedef float f32x16 __attribute__((ext_vector_type(16)));
typedef u16 u16x8 __attribute__((ext_vector_type(8)));

#define DIM 96
#define PLANE (DIM*DIM)   // 9216
#define S 884736          // 96^3
#define C 64
#define HALF 32
#define PARTS 16
#define EPS 1e-5f
#define DSPLIT 8
#define DCHUNK (DIM/DSPLIT)  // 12, divisible by 3 (ring rotation static)

#define MFMA32(a,b,c) __builtin_amdgcn_mfma_f32_32x32x16_bf16(a,b,c,0,0,0)

__device__ __forceinline__ u16 f2bf(float f) {          // RNE, finite inputs
  u32 u = __builtin_bit_cast(u32, f);
  return (u16)((u + 0x7FFFu + ((u >> 16) & 1u)) >> 16);
}
__device__ __forceinline__ float bf2f(u16 h) {
  return __builtin_bit_cast(float, (u32)h << 16);
}
__device__ __forceinline__ u32 cvt_pk_bf16(float lo, float hi) {  // lo->[15:0], hi->[31:16]
  u32 r;
  asm("v_cvt_pk_bf16_f32 %0, %1, %2" : "=v"(r) : "v"(lo), "v"(hi));
  return r;
}
__device__ __forceinline__ float silu(float v) { return v / (1.f + __expf(-v)); }
__device__ __forceinline__ u16x8 zero8() {
  u16x8 z;
  #pragma unroll
  for (int i = 0; i < 8; ++i) z[i] = 0;
  return z;
}
__device__ __forceinline__ void zrow(float* __restrict__ r) {
  #pragma unroll
  for (int i = 0; i < 10; ++i) r[i] = 0.f;
}

// ---- K1: per-channel partial sums (deterministic) + bf16 copy of x -----------
__global__ __launch_bounds__(256) void k1_stats(const float* __restrict__ x,
                                                u16* __restrict__ xb,
                                                float* __restrict__ psum,
                                                float* __restrict__ psq) {
  const int bid = blockIdx.x;              // 0 .. C*PARTS-1
  const int ch = bid / PARTS, part = bid % PARTS;
  const int chunk = S / PARTS;
  const size_t base = (size_t)ch * S + (size_t)part * chunk;
  const float4* p = (const float4*)(x + base);
  ushort4* xb4 = (ushort4*)(xb + base);
  const int n4 = chunk / 4;
  float s = 0.f, q = 0.f;
  for (int i = threadIdx.x; i < n4; i += 256) {
    float4 v = p[i];
    s += (v.x + v.y) + (v.z + v.w);
    q += (v.x * v.x + v.y * v.y) + (v.z * v.z + v.w * v.w);
    union { u32 u[2]; ushort4 v4; } o;
    o.u[0] = cvt_pk_bf16(v.x, v.y);
    o.u[1] = cvt_pk_bf16(v.z, v.w);
    xb4[i] = o.v4;
  }
  #pragma unroll
  for (int off = 32; off > 0; off >>= 1) {
    s += __shfl_down(s, off);
    q += __shfl_down(q, off);
  }
  __shared__ float ls[4], lq[4];
  const int wid = threadIdx.x >> 6, lane = threadIdx.x & 63;
  if (lane == 0) { ls[wid] = s; lq[wid] = q; }
  __syncthreads();
  if (threadIdx.x == 0) {
    psum[bid] = (ls[0] + ls[1]) + (ls[2] + ls[3]);
    psq[bid]  = (lq[0] + lq[1]) + (lq[2] + lq[3]);
  }
}

// ------ K1b: finalize stats; emit bf16 folded in_proj W, bf16 out_proj W ------
__global__ __launch_bounds__(64) void k1b_prep(const float* __restrict__ psum,
    const float* __restrict__ psq,
    const float* __restrict__ norm_w, const float* __restrict__ norm_b,
    const float* __restrict__ in_w, const float* __restrict__ in_b,
    const float* __restrict__ out_w,
    u16* __restrict__ Wp, float* __restrict__ biasp, u16* __restrict__ Wo) {
  __shared__ float a_s[C], b2_s[C];
  const int t = threadIdx.x;               // 0..63 (output row o)
  float s = 0.f, q = 0.f;
  for (int i = 0; i < PARTS; ++i) { s += psum[t * PARTS + i]; q += psq[t * PARTS + i]; }
  const float inv = 1.f / (float)S;
  const float mu = s * inv;
  const float var = q * inv - mu * mu;
  const float rsig = rsqrtf(var + EPS);
  const float a = norm_w[t] * rsig;
  const float b2 = norm_b[t] - mu * a;
  a_s[t] = a; b2_s[t] = b2;
  __syncthreads();
  float bp = in_b[t];
  for (int c = 0; c < C; ++c) {
    const float w = in_w[t * C + c];
    Wp[t * C + c] = f2bf(w * a_s[c]);      // folded norm scale, row-major [o][c]
    bp += b2_s[c] * w;                     // folded norm shift
    Wo[t * C + c] = f2bf(out_w[t * C + c]);
  }
  biasp[t] = bp;
}

// ------ K2: 1x1 in_proj, 32x32x16 MFMA, even/odd interleaved voxel tiles ------
__global__ __launch_bounds__(256) void k2_mfma(const u16* __restrict__ xb,
    const u16* __restrict__ Wp, const float* __restrict__ biasp,
    u16* __restrict__ xp) {
  const int lane = threadIdx.x & 63, wid = threadIdx.x >> 6;
  const int n = lane & 31, hf = lane >> 5;
  const int v0 = blockIdx.x * 256 + wid * 64;      // 64 voxels per wave
  bf16x8 A[2][4];                                  // [o-tile][k-slice]
  #pragma unroll
  for (int t = 0; t < 2; ++t)
    #pragma unroll
    for (int s = 0; s < 4; ++s)
      A[t][s] = *(const bf16x8*)(Wp + (t * 32 + n) * C + s * 16 + hf * 8);

  f32x16 accE[2], accO[2];
  #pragma unroll
  for (int t = 0; t < 2; ++t)
    #pragma unroll
    for (int r = 0; r < 16; ++r) {
      const float b = biasp[t * 32 + (r & 3) + 8 * (r >> 2) + 4 * hf];
      accE[t][r] = b; accO[t][r] = b;
    }

  #pragma unroll
  for (int s = 0; s < 4; ++s) {
    union { u16 u[8]; bf16x8 v; } BE, BO;
    #pragma unroll
    for (int j = 0; j < 8; ++j) {
      const u32 xv = *(const u32*)(xb + (size_t)(s * 16 + hf * 8 + j) * S + v0 + 2 * n);
      BE.u[j] = (u16)(xv & 0xFFFFu); BO.u[j] = (u16)(xv >> 16);
    }
    #pragma unroll
    for (int t = 0; t < 2; ++t) {
      accE[t] = MFMA32(A[t][s], BE.v, accE[t]);
      accO[t] = MFMA32(A[t][s], BO.v, accO[t]);
    }
  }
  #pragma unroll
  for (int t = 0; t < 2; ++t)
    #pragma unroll
    for (int r = 0; r < 16; ++r) {
      const int o = t * 32 + (r & 3) + 8 * (r >> 2) + 4 * hf;
      *(u32*)(xp + (size_t)o * S + v0 + 2 * n) = cvt_pk_bf16(accE[t][r], accO[t][r]);
    }
}

// ------- sliding-window depthwise 3x3x3, bf16 I/O, 8-wide, prefetch-1 ---------
__device__ __forceinline__ void fma_row8(float* __restrict__ a,
    const float* __restrict__ r, float t0, float t1, float t2) {
  #pragma unroll
  for (int i = 0; i < 8; ++i) a[i] += t0 * r[i] + t1 * r[i + 1] + t2 * r[i + 2];
}

// convA: c<32: t1[c] = SiLU(conv_ssm(xp[c])); c>=32: z_hi[c-32] = SiLU(conv_sym(xp[c]))
// convB: z_lo[c] = conv_mamba(t1[c])
template<bool SILU>
__global__ __launch_bounds__(192) void dwconv(const u16* __restrict__ srcA,
    const float* __restrict__ kwA, const float* __restrict__ bA,
    u16* __restrict__ dstA,
    const float* __restrict__ kwB, const float* __restrict__ bB,
    u16* __restrict__ dstB) {
  const int c = blockIdx.z;
  const u16* src = srcA + (size_t)c * S;
  u16* dst; const float* kwp; float bias;
  if (c < HALF) { dst = dstA + (size_t)c * S;          kwp = kwA + c * 27;          bias = bA[c]; }
  else          { dst = dstB + (size_t)(c - HALF) * S; kwp = kwB + (c - HALF) * 27; bias = bB[c - HALF]; }
  float kw[27];                            // wave-uniform -> SGPRs
  #pragma unroll
  for (int i = 0; i < 27; ++i) kw[i] = kwp[i];

  const int w8 = threadIdx.x * 8;
  const int h  = blockIdx.x * 16 + threadIdx.y;
  const bool hm = h > 0, hp = h < DIM - 1;
  const bool wlo = w8 > 0, whi = w8 < DIM - 8;
  const int d0 = blockIdx.y * DCHUNK;

  float Wn[3][3][10];                      // f32 window [plane ring][kh][w]
  u16x8 Rm[3]; u16 Rlo[3], Rhi[3];         // raw prefetch of next plane's 3 rows

  // All row loads use immediate offsets from a single advancing plane pointer.
  #define RAWLOAD(PPTR) { \
    const u16* _p = (PPTR); \
    if (hm) { Rm[0] = *(const u16x8*)(_p - DIM); Rlo[0] = wlo ? _p[-DIM - 1] : (u16)0; Rhi[0] = whi ? _p[-DIM + 8] : (u16)0; } \
    else    { Rm[0] = zero8(); Rlo[0] = 0; Rhi[0] = 0; } \
    {         Rm[1] = *(const u16x8*)(_p);       Rlo[1] = wlo ? _p[-1]       : (u16)0; Rhi[1] = whi ? _p[8]        : (u16)0; } \
    if (hp) { Rm[2] = *(const u16x8*)(_p + DIM); Rlo[2] = wlo ? _p[DIM - 1]  : (u16)0; Rhi[2] = whi ? _p[DIM + 8]  : (u16)0; } \
    else    { Rm[2] = zero8(); Rlo[2] = 0; Rhi[2] = 0; } }

  #define CONVERT(PP) { \
    _Pragma("unroll") \
    for (int k = 0; k < 3; ++k) { \
      Wn[PP][k][0] = bf2f(Rlo[k]); \
      _Pragma("unroll") \
      for (int i = 0; i < 8; ++i) Wn[PP][k][1 + i] = bf2f(Rm[k][i]); \
      Wn[PP][k][9] = bf2f(Rhi[k]); } }

  const u16* pb0 = src + h * DIM + w8;
  u16* db = dst + (size_t)d0 * PLANE + h * DIM + w8;

  if (d0 > 0) { RAWLOAD(pb0 + (size_t)(d0 - 1) * PLANE); CONVERT(2); }
  else        { zrow(Wn[2][0]); zrow(Wn[2][1]); zrow(Wn[2][2]); }
  RAWLOAD(pb0 + (size_t)d0 * PLANE); CONVERT(0);
  const u16* pb = pb0 + (size_t)(d0 + 1) * PLANE;
  RAWLOAD(pb);                             // R <- plane d0+1 (d0+1 <= 85 < DIM)

  // Per step: convert R (plane D+1, loaded last step) -> Wn[PP]; issue loads for
  // plane D+2; then 216 FMAs cover the load latency. One pointer add per step.
  #define STEP(D, PM, PC, PP) { \
    if ((D) + 1 < DIM) { CONVERT(PP); } \
    else { zrow(Wn[PP][0]); zrow(Wn[PP][1]); zrow(Wn[PP][2]); } \
    pb += PLANE; \
    if ((D) + 2 < DIM) RAWLOAD(pb); \
    float a[8]; \
    _Pragma("unroll") \
    for (int i = 0; i < 8; ++i) a[i] = bias; \
    fma_row8(a, Wn[PM][0], kw[0],  kw[1],  kw[2]); \
    fma_row8(a, Wn[PM][1], kw[3],  kw[4],  kw[5]); \
    fma_row8(a, Wn[PM][2], kw[6],  kw[7],  kw[8]); \
    fma_row8(a, Wn[PC][0], kw[9],  kw[10], kw[11]); \
    fma_row8(a, Wn[PC][1], kw[12], kw[13], kw[14]); \
    fma_row8(a, Wn[PC][2], kw[15], kw[16], kw[17]); \
    fma_row8(a, Wn[PP][0], kw[18], kw[19], kw[20]); \
    fma_row8(a, Wn[PP][1], kw[21], kw[22], kw[23]); \
    fma_row8(a, Wn[PP][2], kw[24], kw[25], kw[26]); \
    if (SILU) { \
      _Pragma("unroll") \
      for (int i = 0; i < 8; ++i) a[i] = silu(a[i]); \
    } \
    union { u32 u[4]; u16x8 v; } o; \
    _Pragma("unroll") \
    for (int i = 0; i < 4; ++i) o.u[i] = cvt_pk_bf16(a[2 * i], a[2 * i + 1]); \
    *(u16x8*)db = o.v; \
    db += PLANE; }

  #pragma unroll 1
  for (int it3 = 0; it3 < DCHUNK; it3 += 3) {  // ring indices static per body
    const int d = d0 + it3;
    STEP(d,     2, 0, 1);
    STEP(d + 1, 0, 1, 2);
    STEP(d + 2, 1, 2, 0);
  }
  #undef STEP
  #undef CONVERT
  #undef RAWLOAD
}

// --- K4b: 1x1 out_proj (32x32x16 MFMA) + bias + bf16 residual -> fp32 out -----
__global__ __launch_bounds__(256) void k4b_mfma(const u16* __restrict__ z_lo,
    const u16* __restrict__ z_hi, const u16* __restrict__ xb,
    const u16* __restrict__ Wo, const float* __restrict__ ob,
    float* __restrict__ out) {
  const int lane = threadIdx.x & 63, wid = threadIdx.x >> 6;
  const int n = lane & 31, hf = lane >> 5;
  const int v0 = blockIdx.x * 256 + wid * 64;
  bf16x8 A[2][4];
  #pragma unroll
  for (int t = 0; t < 2; ++t)
    #pragma unroll
    for (int s = 0; s < 4; ++s)
      A[t][s] = *(const bf16x8*)(Wo + (t * 32 + n) * C + s * 16 + hf * 8);

  f32x16 accE[2], accO[2];
  #pragma unroll
  for (int t = 0; t < 2; ++t)
    #pragma unroll
    for (int r = 0; r < 16; ++r) {
      const float b = ob[t * 32 + (r & 3) + 8 * (r >> 2) + 4 * hf];
      accE[t][r] = b; accO[t][r] = b;
    }

  #pragma unroll
  for (int s = 0; s < 4; ++s) {
    const u16* zbase = (s < 2) ? z_lo + (size_t)(s * 16) * S
                               : z_hi + (size_t)((s - 2) * 16) * S;
    union { u16 u[8]; bf16x8 v; } BE, BO;
    #pragma unroll
    for (int j = 0; j < 8; ++j) {
      const u32 zv = *(const u32*)(zbase + (size_t)(hf * 8 + j) * S + v0 + 2 * n);
      BE.u[j] = (u16)(zv & 0xFFFFu); BO.u[j] = (u16)(zv >> 16);
    }
    #pragma unroll
    for (int t = 0; t < 2; ++t) {
      accE[t] = MFMA32(A[t][s], BE.v, accE[t]);
      accO[t] = MFMA32(A[t][s], BO.v, accO[t]);
    }
  }
  #pragma unroll
  for (int t = 0; t < 2; ++t)
    #pragma unroll
    for (int r = 0; r < 16; ++r) {
      const int o = t * 32 + (r & 3) + 8 * (r >> 2) + 4 * hf;
      const u32 xr = *(const u32*)(xb + (size_t)o * S + v0 + 2 * n);
      float2 ov;
      ov.x = accE[t][r] + bf2f((u16)(xr & 0xFFFFu));
      ov.y = accO[t][r] + bf2f((u16)(xr >> 16));
      *(float2*)(out + (size_t)o * S + v0 + 2 * n) = ov;
    }
}

extern "C" void kernel_launch(void* const* d_in, const int* in_sizes, int n_in,
                              void* d_out, int out_size, void* d_ws, size_t ws_size,
                              hipStream_t stream) {
  const float* x      = (const float*)d_in[0];
  const float* norm_w = (const float*)d_in[1];
  const float* norm_b = (const float*)d_in[2];
  const float* in_w   = (const float*)d_in[3];
  const float* in_b   = (const float*)d_in[4];
  const float* ssm_w  = (const float*)d_in[5];
  const float* ssm_b  = (const float*)d_in[6];
  const float* mam_w  = (const float*)d_in[7];
  const float* mam_b  = (const float*)d_in[8];
  const float* sym_w  = (const float*)d_in[9];
  const float* sym_b  = (const float*)d_in[10];
  const float* out_w  = (const float*)d_in[11];
  const float* out_b  = (const float*)d_in[12];
  float* out = (float*)d_out;

  // Workspace (u16 units). z_lo ALIASES xp[0:32] (dead after convA; convB is
  // launched after convA completes, stream-ordered). Total ~340 MB.
  u16* xb   = (u16*)d_ws;                      // C*S bf16 copy of x (113.2 MB)
  u16* xp   = xb + (size_t)C * S;              // C*S bf16 (113.2 MB)
  u16* t1   = xp + (size_t)C * S;              // HALF*S bf16 (56.6 MB)
  u16* z_hi = t1 + (size_t)HALF * S;           // HALF*S bf16 (56.6 MB)
  u16* z_lo = xp;                              // alias, HALF*S
  float* psum  = (float*)(z_hi + (size_t)HALF * S);  // C*PARTS
  float* psq   = psum + C * PARTS;             // C*PARTS
  u16* Wp      = (u16*)(psq + C * PARTS);      // C*C bf16
  u16* Wo      = Wp + C * C;                   // C*C bf16
  float* biasp = (float*)(Wo + C * C);         // C fp32

  k1_stats<<<C * PARTS, 256, 0, stream>>>(x, xb, psum, psq);
  k1b_prep<<<1, 64, 0, stream>>>(psum, psq, norm_w, norm_b, in_w, in_b, out_w,
                                 Wp, biasp, Wo);
  k2_mfma<<<S / 256, 256, 0, stream>>>(xb, Wp, biasp, xp);
  // convA: ssm on xp[0:32] -> t1 ; sym on xp[32:64] -> z_hi (both SiLU)
  dwconv<true><<<dim3(DIM / 16, DSPLIT, C), dim3(12, 16, 1), 0, stream>>>(
      xp, ssm_w, ssm_b, t1, sym_w, sym_b, z_hi);
  // convB: mamba on t1 -> z_lo (no activation)
  dwconv<false><<<dim3(DIM / 16, DSPLIT, HALF), dim3(12, 16, 1), 0, stream>>>(
      t1, mam_w, mam_b, z_lo, mam_w, mam_b, z_lo);
  k4b_mfma<<<S / 256, 256, 0, stream>>>(z_lo, z_hi, xb, Wo, out_b, out);
}